// Round 6
// baseline (3832.816 us; speedup 1.0000x reference)
//
#include <hip/hip_runtime.h>

#define P_   24
#define H_   24
#define E_   300
#define D_   512
#define TWOD 1024
#define G4   4096
#define SMEMB  27648            // p1 staging (27.6 KB) >= gates Dt (16.9 KB)
#define SMEMD  17024

typedef __attribute__((ext_vector_type(8))) short bf16x8;
typedef __attribute__((ext_vector_type(4))) float f32x4;

__device__ __forceinline__ float bflo(unsigned w) { return __uint_as_float(w << 16); }
__device__ __forceinline__ float bfhi(unsigned w) { return __uint_as_float(w & 0xffff0000u); }
__device__ __forceinline__ unsigned short f2bf(float f) {
    unsigned int x = __float_as_uint(f);
    unsigned int r = (x + 0x7fffu + ((x >> 16) & 1u)) >> 16;
    return (unsigned short)r;
}
__device__ __forceinline__ float sigf(float x) {
    return 1.0f / (1.0f + __expf(-x));
}
__device__ __forceinline__ float tanh_f(float x) {
    return 2.0f / (1.0f + __expf(-2.0f * x)) - 1.0f;
}

// fabric-coherent relaxed agent-scope accessors (HW-coherent across XCDs,
// L2-allocating — R3: FETCH matched cached-traffic model). NO acquire/release
// anywhere (agent-acquire => buffer_inv kills warm L2). Dynamic state
// (H/C/H2B/C2B) is written AND read through these; read-only data (weights,
// Apre/Cpre after their producing phase) uses plain cached loads — safe
// because the kernel-launch implicit acquire invalidated L2 before first
// touch, and those lines are never rewritten within the kernel.
#define CFENCE() asm volatile("" ::: "memory")
#define LD8(p)   __hip_atomic_load((const unsigned long long*)(p), __ATOMIC_RELAXED, __HIP_MEMORY_SCOPE_AGENT)
#define ST8(p,v) __hip_atomic_store((unsigned long long*)(p), (unsigned long long)(v), __ATOMIC_RELAXED, __HIP_MEMORY_SCOPE_AGENT)
#define LDF(p)   __hip_atomic_load((const float*)(p), __ATOMIC_RELAXED, __HIP_MEMORY_SCOPE_AGENT)
#define LDU(p)   __hip_atomic_load((const unsigned*)(p), __ATOMIC_RELAXED, __HIP_MEMORY_SCOPE_AGENT)
#define STU(p,v) __hip_atomic_store((unsigned*)(p), (unsigned)(v), __ATOMIC_RELAXED, __HIP_MEMORY_SCOPE_AGENT)
#define STF(p,v) __hip_atomic_store((float*)(p), (float)(v), __ATOMIC_RELAXED, __HIP_MEMORY_SCOPE_AGENT)
#define AADD(p,v) __hip_atomic_fetch_add((unsigned*)(p), (unsigned)(v), __ATOMIC_RELAXED, __HIP_MEMORY_SCOPE_AGENT)

// 16B coherent fragment load (two 8B fabric loads)
__device__ __forceinline__ bf16x8 lda16(const unsigned short* p) {
    union { unsigned long long u[2]; bf16x8 v; } w;
    w.u[0] = LD8(p); w.u[1] = LD8(p + 4);
    return w.v;
}

// ---------------- workspace byte offsets ----------------
#define OFF_WHHP 0u           // packed Whh bf16: [nt=32][q=4][u=32][k=1024]
#define OFF_WCHB 8388608u     // 512*1024 bf16
#define OFF_WCCB 9437184u     // 512*1024 bf16
#define OFF_APRE 10485760u    // 768*4096 bf16
#define OFF_CPRE 16777216u    // 768*4096 bf16
#define OFF_PX   23068672u    // 768*320 bf16
#define OFF_HX   23560192u    // 768*320 bf16
#define OFF_HBB  24051712u    // 2*24*32*512 bf16 (h state, parity buffers)
#define OFF_CBF  25624576u    // 2*24*32*512 f32  (c state)
#define OFF_H2B  28770304u    // 24*32*1024 bf16
#define OFF_C2B  30343168u    // 24*32*1024 bf16
#define OFF_HF   31916032u    // 24*32*512 f32 (final h for MLP)
#define OFF_T1   33488896u    // 32*512 f32
#define OFF_T2   33554432u    // 32*512 f32
#define OFF_FLG  33619968u    // per-(diagonal,cell) arrival counters 47*24 u32 (8 KiB rsvd)
#define OFF_BAR2 33628160u    // barrier: 32 cnt lines, central, 32 gen lines (10 KiB)
#define ZERO_BYTES 18432u     // memset span: FLG + BAR2

// ============ P0 body: weight convert/pack + embedding gather ==============
__device__ __forceinline__ void p0_body(
        int gt, int stride,
        const int* __restrict__ prem, const int* __restrict__ hyp,
        const float* __restrict__ emb, const float* __restrict__ Whh,
        const float* __restrict__ Wch, const float* __restrict__ Wcc,
        char* __restrict__ wsb) {
    unsigned short* WhhP = (unsigned short*)(wsb + OFF_WHHP);
    unsigned short* WchB = (unsigned short*)(wsb + OFF_WCHB);
    unsigned short* WccB = (unsigned short*)(wsb + OFF_WCCB);
    unsigned short* PX   = (unsigned short*)(wsb + OFF_PX);
    unsigned short* HX   = (unsigned short*)(wsb + OFF_HX);

    // Whh: convert + permute rows n=q*1024+nt*32+u -> pr=nt*128+q*32+u
    for (int idx = gt; idx < 524288; idx += stride) {
        int n = idx >> 7;              // original row
        int k8 = (idx & 127) * 8;      // col start
        int q = n >> 10, rest = n & 1023;
        int nt = rest >> 5, u = rest & 31;
        int pr = nt * 128 + q * 32 + u;
        const float* s = Whh + (size_t)n * TWOD + k8;
        float4 va = *(const float4*)s, vb = *(const float4*)(s + 4);
        unsigned long long w0 = (unsigned long long)f2bf(va.x)
            | ((unsigned long long)f2bf(va.y) << 16)
            | ((unsigned long long)f2bf(va.z) << 32)
            | ((unsigned long long)f2bf(va.w) << 48);
        unsigned long long w1 = (unsigned long long)f2bf(vb.x)
            | ((unsigned long long)f2bf(vb.y) << 16)
            | ((unsigned long long)f2bf(vb.z) << 32)
            | ((unsigned long long)f2bf(vb.w) << 48);
        unsigned short* dp = WhhP + (size_t)pr * TWOD + k8;
        ST8(dp, w0); ST8(dp + 4, w1);
    }
    for (int idx = gt; idx < 131072; idx += stride) {
        int cc = idx & 65535;
        const float* s = ((idx < 65536) ? Wch : Wcc) + (size_t)cc * 8;
        unsigned short* dp = ((idx < 65536) ? WchB : WccB) + (size_t)cc * 8;
        float4 va = *(const float4*)s, vb = *(const float4*)(s + 4);
        unsigned long long w0 = (unsigned long long)f2bf(va.x)
            | ((unsigned long long)f2bf(va.y) << 16)
            | ((unsigned long long)f2bf(va.z) << 32)
            | ((unsigned long long)f2bf(va.w) << 48);
        unsigned long long w1 = (unsigned long long)f2bf(vb.x)
            | ((unsigned long long)f2bf(vb.y) << 16)
            | ((unsigned long long)f2bf(vb.z) << 32)
            | ((unsigned long long)f2bf(vb.w) << 48);
        ST8(dp, w0); ST8(dp + 4, w1);
    }
    for (int idx = gt; idx < 61440; idx += stride) {
        int isH = idx >= 30720 ? 1 : 0;
        int id2 = idx - isH * 30720;
        int rb = id2 / 40, c8 = (id2 % 40) * 8;
        int ri = rb >> 5, rbb = rb & 31;
        int tok = isH ? hyp[rbb * H_ + ri] : prem[rbb * P_ + ri];
        const float* s = emb + (size_t)tok * E_ + c8;
        unsigned short o[8];
        for (int e = 0; e < 8; ++e)
            o[e] = (c8 + e < E_) ? f2bf(s[e]) : (unsigned short)0;
        unsigned long long w0 = (unsigned long long)o[0]
            | ((unsigned long long)o[1] << 16)
            | ((unsigned long long)o[2] << 32)
            | ((unsigned long long)o[3] << 48);
        unsigned long long w1 = (unsigned long long)o[4]
            | ((unsigned long long)o[5] << 16)
            | ((unsigned long long)o[6] << 32)
            | ((unsigned long long)o[7] << 48);
        unsigned short* dp = (isH ? HX : PX) + rb * 320 + c8;
        ST8(dp, w0); ST8(dp + 4, w1);
    }
}

// ============ P1 body: Apre/Cpre GEMM, 64x128 tiles, K=320 =================
__device__ __forceinline__ void p1_body(
        int q, const float* __restrict__ Wih, const float* __restrict__ bih,
        const float* __restrict__ bhh, char* __restrict__ wsb,
        unsigned char* smem) {
    const unsigned short* PX = (const unsigned short*)(wsb + OFF_PX);
    const unsigned short* HX = (const unsigned short*)(wsb + OFF_HX);
    unsigned short* Apre = (unsigned short*)(wsb + OFF_APRE);
    unsigned short* Cpre = (unsigned short*)(wsb + OFF_CPRE);

    const int t = threadIdx.x;
    const int lane = t & 63, wvi = t >> 6, l16 = lane & 15, quad = lane >> 4;
    const int wm = wvi >> 1, wn = wvi & 1;
    unsigned short (*At)[72] = (unsigned short (*)[72])smem;            // 64 rows
    unsigned short (*Bt)[72] = (unsigned short (*)[72])(smem + 9216);   // 128 rows

    int x = q & 7, slot = q >> 3;
    int z = slot / 48, rem = slot % 48;
    int ntg = rem / 12, mt = rem % 12;
    int nt = ntg * 8 + x;
    const unsigned short* X = z ? HX : PX;
    int koff = z ? E_ : 0;
    unsigned short* Out = z ? Cpre : Apre;
    f32x4 acc[2][4] = {};
    int arow = t >> 2, acol = (t & 3) * 16;
    int brow = t >> 1, bcol = (t & 1) * 32;
    for (int s = 0; s < 5; ++s) {
        int k0 = s * 64;
        {
            const unsigned short* sp = X + (size_t)(mt * 64 + arow) * 320 + k0 + acol;
            unsigned long long x0 = LD8(sp), x1 = LD8(sp + 4);
            unsigned long long x2 = LD8(sp + 8), x3 = LD8(sp + 12);
            unsigned long long* dst = (unsigned long long*)&At[arow][acol];
            dst[0] = x0; dst[1] = x1; dst[2] = x2; dst[3] = x3;
        }
        {
            int n = nt * 128 + brow;
            const float* wrow = Wih + (size_t)n * (2 * E_) + koff;
            unsigned short* dst = &Bt[brow][bcol];
            for (int c4 = 0; c4 < 8; ++c4) {
                int k = k0 + bcol + c4 * 4;
                if (k < E_) {
                    float4 v = *(const float4*)(wrow + k);
                    dst[c4 * 4 + 0] = f2bf(v.x); dst[c4 * 4 + 1] = f2bf(v.y);
                    dst[c4 * 4 + 2] = f2bf(v.z); dst[c4 * 4 + 3] = f2bf(v.w);
                } else {
                    dst[c4 * 4 + 0] = 0; dst[c4 * 4 + 1] = 0;
                    dst[c4 * 4 + 2] = 0; dst[c4 * 4 + 3] = 0;
                }
            }
        }
        __syncthreads();
        for (int ks = 0; ks < 2; ++ks) {
            bf16x8 a[2], bb[4];
            for (int mi = 0; mi < 2; ++mi)
                a[mi] = *(const bf16x8*)&At[wm * 32 + mi * 16 + l16][ks * 32 + quad * 8];
            for (int ni = 0; ni < 4; ++ni)
                bb[ni] = *(const bf16x8*)&Bt[wn * 64 + ni * 16 + l16][ks * 32 + quad * 8];
            for (int mi = 0; mi < 2; ++mi)
                for (int ni = 0; ni < 4; ++ni)
                    acc[mi][ni] = __builtin_amdgcn_mfma_f32_16x16x32_bf16(
                        a[mi], bb[ni], acc[mi][ni], 0, 0, 0);
        }
        __syncthreads();
    }
    for (int mi = 0; mi < 2; ++mi) {
        int rbase = mt * 64 + wm * 32 + mi * 16 + quad * 4;
        for (int ni = 0; ni < 4; ++ni) {
            int n = nt * 128 + wn * 64 + ni * 16 + l16;
            float bias = z ? 0.0f : (bih[n] + bhh[n]);
            for (int r = 0; r < 4; ++r) {
                float val = acc[mi][ni][r] + bias;
                float pv = __shfl_xor(val, 1);
                if ((lane & 1) == 0) {
                    unsigned w2 = (unsigned)f2bf(val) | ((unsigned)f2bf(pv) << 16);
                    STU(&Out[(size_t)(rbase + r) * G4 + n], w2);
                }
            }
        }
    }
    __syncthreads();   // protect smem before caller's next phase
}

// ====== gates job body: fragment-direct GEMM, NO LDS staging, NO K-loop ====
// barriers. B (Whh slice) is per-wave private -> plain 16B fragment loads
// straight from L2 (64B-coalesced per 4-lane group). A (h state, cross-XCD
// dynamic) -> coherent LD8 fragment loads, read 4x (once per wave).
// 1-step register double-buffer, fully unrolled (static indices).
__device__ __forceinline__ void gates_job(
        int d, int ncells, int j_lo, int job,
        char* __restrict__ wsb, unsigned char* smem, unsigned* flg) {
    const unsigned short* WhhP = (const unsigned short*)(wsb + OFF_WHHP);
    const unsigned short* Apre = (const unsigned short*)(wsb + OFF_APRE);
    const unsigned short* Cpre = (const unsigned short*)(wsb + OFF_CPRE);
    const unsigned short* HbB  = (const unsigned short*)(wsb + OFF_HBB);
    const float*          Cbf  = (const float*)(wsb + OFF_CBF);
    unsigned short* H2B = (unsigned short*)(wsb + OFF_H2B);
    unsigned short* C2B = (unsigned short*)(wsb + OFF_C2B);

    int x = job & 7, slot = job >> 3;
    int ntg = slot / ncells, c = slot - ntg * ncells;
    int nt = ntg * 8 + x;
    int cj = j_lo + c, ci = d - cj;

    const unsigned short* HpB = HbB + (size_t)((d + 1) & 1) * (H_ * 32 * D_);
    const float* Cp = Cbf + (size_t)((d + 1) & 1) * (H_ * 32 * D_);

    const int t = threadIdx.x;
    const int lane = t & 63, wvi = t >> 6, l16 = lane & 15, quad = lane >> 4;

    // B fragment rows (per-wave private slice of WhhP)
    const unsigned short* wrow0 = WhhP + (size_t)(nt * 128 + wvi * 32 + l16) * TWOD;
    const unsigned short* wrow1 = wrow0 + (size_t)16 * TWOD;
    // A fragment rows: left-h (k<512) and lower-h (k>=512) halves
    const unsigned short* aL0 = (ci > 0) ? HpB + (size_t)(cj * 32 + l16) * D_ : nullptr;
    const unsigned short* aL1 = (ci > 0) ? HpB + (size_t)(cj * 32 + 16 + l16) * D_ : nullptr;
    const unsigned short* aD0 = (cj > 0) ? HpB + (size_t)((cj - 1) * 32 + l16) * D_ : nullptr;
    const unsigned short* aD1 = (cj > 0) ? HpB + (size_t)((cj - 1) * 32 + 16 + l16) * D_ : nullptr;

    const bf16x8 kz = {};
    f32x4 acc[2][2] = {};
    bf16x8 fa00[2], fa01[2], fa10[2], fa11[2];
    bf16x8 fb00[2], fb01[2], fb10[2], fb11[2];

    // A fragment at col `co` (0..1023): half-select is compile-time per step
    #define GAF(r_, co_) \
        (((co_) < D_) ? ((r_##0_) ? lda16(r_##0_ + (co_)) : kz) \
                      : ((r_##1_) ? lda16(r_##1_ + ((co_) - D_)) : kz))

    #define GLD(b_, s_) do {                                                   \
            const int co0 = (s_) * 64 + quad * 8;                              \
            const int co1 = co0 + 32;                                          \
            fa00[b_] = (co0 < D_) ? (aL0 ? lda16(aL0 + co0) : kz)              \
                                  : (aD0 ? lda16(aD0 + co0 - D_) : kz);        \
            fa01[b_] = (co1 < D_) ? (aL0 ? lda16(aL0 + co1) : kz)              \
                                  : (aD0 ? lda16(aD0 + co1 - D_) : kz);        \
            fa10[b_] = (co0 < D_) ? (aL1 ? lda16(aL1 + co0) : kz)              \
                                  : (aD1 ? lda16(aD1 + co0 - D_) : kz);        \
            fa11[b_] = (co1 < D_) ? (aL1 ? lda16(aL1 + co1) : kz)              \
                                  : (aD1 ? lda16(aD1 + co1 - D_) : kz);        \
            fb00[b_] = *(const bf16x8*)(wrow0 + co0);                          \
            fb01[b_] = *(const bf16x8*)(wrow0 + co1);                          \
            fb10[b_] = *(const bf16x8*)(wrow1 + co0);                          \
            fb11[b_] = *(const bf16x8*)(wrow1 + co1);                          \
        } while (0)

    GLD(0, 0);
    #pragma unroll
    for (int s = 0; s < 16; ++s) {
        const int c_ = s & 1;
        if (s < 15) GLD(1 - c_, s + 1);
        acc[0][0] = __builtin_amdgcn_mfma_f32_16x16x32_bf16(fa00[c_], fb00[c_], acc[0][0], 0, 0, 0);
        acc[0][1] = __builtin_amdgcn_mfma_f32_16x16x32_bf16(fa00[c_], fb10[c_], acc[0][1], 0, 0, 0);
        acc[1][0] = __builtin_amdgcn_mfma_f32_16x16x32_bf16(fa10[c_], fb00[c_], acc[1][0], 0, 0, 0);
        acc[1][1] = __builtin_amdgcn_mfma_f32_16x16x32_bf16(fa10[c_], fb10[c_], acc[1][1], 0, 0, 0);
        acc[0][0] = __builtin_amdgcn_mfma_f32_16x16x32_bf16(fa01[c_], fb01[c_], acc[0][0], 0, 0, 0);
        acc[0][1] = __builtin_amdgcn_mfma_f32_16x16x32_bf16(fa01[c_], fb11[c_], acc[0][1], 0, 0, 0);
        acc[1][0] = __builtin_amdgcn_mfma_f32_16x16x32_bf16(fa11[c_], fb01[c_], acc[1][0], 0, 0, 0);
        acc[1][1] = __builtin_amdgcn_mfma_f32_16x16x32_bf16(fa11[c_], fb11[c_], acc[1][1], 0, 0, 0);
    }
    #undef GLD
    #undef GAF

    // epilogue: cross-wave gate exchange via LDS (gate q = wvi), then fused
    // LSTM activation.
    float* Dt = (float*)smem;   // [32][132]
    for (int mi = 0; mi < 2; ++mi)
        for (int ni = 0; ni < 2; ++ni) {
            int cc2 = wvi * 32 + ni * 16 + l16;
            int rr = mi * 16 + quad * 4;
            for (int r = 0; r < 4; ++r)
                Dt[(rr + r) * 132 + cc2] = acc[mi][ni][r];
        }
    __syncthreads();
    {
        int u2 = (t & 15) * 2, r0 = (t >> 4) * 2;
        int k = nt * 32 + u2;            // even -> 4B-aligned pairs
        for (int r = r0; r < r0 + 2; ++r) {
            size_t ai = (size_t)(ci * 32 + r) * G4 + k;
            size_t cix = (size_t)(cj * 32 + r) * G4 + k;
            unsigned ap0 = *(const unsigned*)&Apre[ai];
            unsigned ap1 = *(const unsigned*)&Apre[ai + 1024];
            unsigned ap2 = *(const unsigned*)&Apre[ai + 2048];
            unsigned ap3 = *(const unsigned*)&Apre[ai + 3072];
            unsigned cp0 = *(const unsigned*)&Cpre[cix];
            unsigned cp1 = *(const unsigned*)&Cpre[cix + 1024];
            unsigned cp2 = *(const unsigned*)&Cpre[cix + 2048];
            unsigned cp3 = *(const unsigned*)&Cpre[cix + 3072];
            float ccat0, ccat1;
            if (k < D_) {
                if (ci > 0) {
                    const float* cp = Cp + (size_t)(cj * 32 + r) * D_ + k;
                    ccat0 = LDF(cp); ccat1 = LDF(cp + 1);
                } else { ccat0 = 0.0f; ccat1 = 0.0f; }
            } else {
                if (cj > 0) {
                    const float* cp = Cp + (size_t)((cj - 1) * 32 + r) * D_ + (k - D_);
                    ccat0 = LDF(cp); ccat1 = LDF(cp + 1);
                } else { ccat0 = 0.0f; ccat1 = 0.0f; }
            }
            float g00 = Dt[r * 132 +      u2]     + bflo(ap0) + bflo(cp0);
            float g01 = Dt[r * 132 +      u2 + 1] + bfhi(ap0) + bfhi(cp0);
            float g10 = Dt[r * 132 + 32 + u2]     + bflo(ap1) + bflo(cp1);
            float g11 = Dt[r * 132 + 32 + u2 + 1] + bfhi(ap1) + bfhi(cp1);
            float g20 = Dt[r * 132 + 64 + u2]     + bflo(ap2) + bflo(cp2);
            float g21 = Dt[r * 132 + 64 + u2 + 1] + bfhi(ap2) + bfhi(cp2);
            float g30 = Dt[r * 132 + 96 + u2]     + bflo(ap3) + bflo(cp3);
            float g31 = Dt[r * 132 + 96 + u2 + 1] + bfhi(ap3) + bfhi(cp3);
            float c20 = sigf(g10) * ccat0 + sigf(g00) * tanh_f(g20);
            float h20 = sigf(g30) * tanh_f(c20);
            float c21 = sigf(g11) * ccat1 + sigf(g01) * tanh_f(g21);
            float h21 = sigf(g31) * tanh_f(c21);
            unsigned hw = (unsigned)f2bf(h20) | ((unsigned)f2bf(h21) << 16);
            unsigned cw = (unsigned)f2bf(c20) | ((unsigned)f2bf(c21) << 16);
            STU(&H2B[(size_t)(c * 32 + r) * TWOD + k], hw);
            STU(&C2B[(size_t)(c * 32 + r) * TWOD + k], cw);
        }
    }
    // all waves drain their fabric stores at this barrier, then publish.
    __syncthreads();
    if (t == 0) { CFENCE(); AADD(&flg[c], 1u); CFENCE(); }
}

// ====== cond job body: fragment-direct GEMM, no LDS at all ================
__device__ __forceinline__ void cond_job(
        int d, int j_lo, int job,
        const float* __restrict__ bch, const float* __restrict__ bcc,
        char* __restrict__ wsb, unsigned char* smem, unsigned* flg) {
    (void)smem;
    const unsigned short* H2B  = (const unsigned short*)(wsb + OFF_H2B);
    const unsigned short* C2B  = (const unsigned short*)(wsb + OFF_C2B);
    const unsigned short* WchB = (const unsigned short*)(wsb + OFF_WCHB);
    const unsigned short* WccB = (const unsigned short*)(wsb + OFF_WCCB);
    unsigned short* HbB = (unsigned short*)(wsb + OFF_HBB);
    float* Cbf = (float*)(wsb + OFF_CBF);
    float* Hf  = (float*)(wsb + OFF_HF);

    int xcd = job & 7, c = job >> 3;
    int z = xcd >> 2, ntile = xcd & 3;
    const unsigned short* Ain = z ? C2B : H2B;
    const unsigned short* W = z ? WccB : WchB;
    int cj = j_lo + c;

    const int t = threadIdx.x;
    const int lane = t & 63, wvi = t >> 6, l16 = lane & 15, quad = lane >> 4;

    unsigned short* HbC = HbB + (size_t)(d & 1) * (H_ * 32 * D_);
    float* CbC = Cbf + (size_t)(d & 1) * (H_ * 32 * D_);

    // wait: all 32 gates jobs of this cell published (monotonic slot flg[c])
    if (t == 0) {
        CFENCE();
        while (LDU(&flg[c]) < 32u)
            __builtin_amdgcn_s_sleep(1);
        CFENCE();
    }
    __syncthreads();

    const unsigned short* arow0 = Ain + (size_t)(c * 32 + l16) * TWOD;
    const unsigned short* arow1 = Ain + (size_t)(c * 32 + 16 + l16) * TWOD;
    const unsigned short* wrow0 = W + (size_t)(ntile * 128 + wvi * 32 + l16) * TWOD;
    const unsigned short* wrow1 = wrow0 + (size_t)16 * TWOD;

    f32x4 acc[2][2] = {};
    bf16x8 fa00[2], fa01[2], fa10[2], fa11[2];
    bf16x8 fb00[2], fb01[2], fb10[2], fb11[2];

    #define CLD(b_, s_) do {                                                   \
            const int co0 = (s_) * 64 + quad * 8;                              \
            const int co1 = co0 + 32;                                          \
            fa00[b_] = lda16(arow0 + co0);                                     \
            fa01[b_] = lda16(arow0 + co1);                                     \
            fa10[b_] = lda16(arow1 + co0);                                     \
            fa11[b_] = lda16(arow1 + co1);                                     \
            fb00[b_] = *(const bf16x8*)(wrow0 + co0);                          \
            fb01[b_] = *(const bf16x8*)(wrow0 + co1);                          \
            fb10[b_] = *(const bf16x8*)(wrow1 + co0);                          \
            fb11[b_] = *(const bf16x8*)(wrow1 + co1);                          \
        } while (0)

    CLD(0, 0);
    #pragma unroll
    for (int s = 0; s < 16; ++s) {
        const int c_ = s & 1;
        if (s < 15) CLD(1 - c_, s + 1);
        acc[0][0] = __builtin_amdgcn_mfma_f32_16x16x32_bf16(fa00[c_], fb00[c_], acc[0][0], 0, 0, 0);
        acc[0][1] = __builtin_amdgcn_mfma_f32_16x16x32_bf16(fa00[c_], fb10[c_], acc[0][1], 0, 0, 0);
        acc[1][0] = __builtin_amdgcn_mfma_f32_16x16x32_bf16(fa10[c_], fb00[c_], acc[1][0], 0, 0, 0);
        acc[1][1] = __builtin_amdgcn_mfma_f32_16x16x32_bf16(fa10[c_], fb10[c_], acc[1][1], 0, 0, 0);
        acc[0][0] = __builtin_amdgcn_mfma_f32_16x16x32_bf16(fa01[c_], fb01[c_], acc[0][0], 0, 0, 0);
        acc[0][1] = __builtin_amdgcn_mfma_f32_16x16x32_bf16(fa01[c_], fb11[c_], acc[0][1], 0, 0, 0);
        acc[1][0] = __builtin_amdgcn_mfma_f32_16x16x32_bf16(fa11[c_], fb01[c_], acc[1][0], 0, 0, 0);
        acc[1][1] = __builtin_amdgcn_mfma_f32_16x16x32_bf16(fa11[c_], fb11[c_], acc[1][1], 0, 0, 0);
    }
    #undef CLD

    for (int mi = 0; mi < 2; ++mi) {
        int rr = mi * 16 + quad * 4;
        for (int ni = 0; ni < 2; ++ni) {
            int n = ntile * 128 + wvi * 32 + ni * 16 + l16;
            float bsv = z ? bcc[n] : bch[n];
            for (int r = 0; r < 4; ++r) {
                int rb = rr + r;
                float val = acc[mi][ni][r] + bsv;
                if (z) {
                    STF(&CbC[(size_t)(cj * 32 + rb) * D_ + n], val);
                } else {
                    float pv = __shfl_xor(val, 1);
                    if ((lane & 1) == 0) {
                        unsigned w2 = (unsigned)f2bf(val) | ((unsigned)f2bf(pv) << 16);
                        STU(&HbC[(size_t)(cj * 32 + rb) * D_ + n], w2);
                    }
                    if (d == P_ + H_ - 2)
                        STF(&Hf[(size_t)(cj * 32 + rb) * D_ + n], val);
                }
            }
        }
    }
}

// ============ MLP head job bodies ==========================================
__device__ __forceinline__ void fc_job(
        const float* __restrict__ hin, const float* __restrict__ W,
        const float* __restrict__ bias, float* __restrict__ outv, int job,
        float* hsh) {
    int t = threadIdx.x;
    int row = job >> 1, cb = (job & 1) * 256;
    const float* h = hin + (size_t)row * D_;
    hsh[t * 2]     = LDF(h + t * 2);
    hsh[t * 2 + 1] = LDF(h + t * 2 + 1);
    __syncthreads();
    int col = cb + t;
    const float* w = W + (size_t)col * D_;
    float accv = bias[col];
    for (int k = 0; k < D_; k += 4) {
        float4 wv4 = *(const float4*)(w + k);
        float4 hv = *(const float4*)(hsh + k);
        accv += hv.x * wv4.x + hv.y * wv4.y + hv.z * wv4.z + hv.w * wv4.w;
    }
    STF(&outv[(size_t)row * D_ + col], fmaxf(accv, 0.0f));
    __syncthreads();
}

__device__ __forceinline__ void sm_job(
        const float* __restrict__ T2, const float* __restrict__ W3,
        const float* __restrict__ b3, float* __restrict__ out, float* lg) {
    int t = threadIdx.x;
    if (t < 96) {
        int rb = t / 3, cls = t % 3;
        const float* h = T2 + (size_t)rb * D_;
        const float* w = W3 + (size_t)cls * D_;
        float accv = b3[cls];
        for (int k = 0; k < D_; k += 4) {
            float4 wv4 = *(const float4*)(w + k);
            accv += LDF(h + k) * wv4.x + LDF(h + k + 1) * wv4.y +
                    LDF(h + k + 2) * wv4.z + LDF(h + k + 3) * wv4.w;
        }
        lg[rb * 3 + cls] = accv;
    }
    __syncthreads();
    if (t < 32) {
        float a = lg[t * 3 + 0], bq = lg[t * 3 + 1], cq = lg[t * 3 + 2];
        float m = fmaxf(a, fmaxf(bq, cq));
        float ea = __expf(a - m), eb = __expf(bq - m), ec = __expf(cq - m);
        float s = 1.0f / (ea + eb + ec);
        out[t * 3 + 0] = ea * s;
        out[t * 3 + 1] = eb * s;
        out[t * 3 + 2] = ec * s;
    }
}

// ============ lightweight monotonic 2-level grid barrier ===================
__device__ __forceinline__ void gbar(unsigned* bs, unsigned idx, int grid) {
    __syncthreads();      // drains each wave's outstanding (fabric) stores
    if (threadIdx.x == 0) {
        unsigned g = blockIdx.x & 31u;
        unsigned gs = (unsigned)grid >> 5;
        CFENCE();
        unsigned old = AADD(bs + g * 32, 1u);
        CFENCE();
        if (old == (idx + 1u) * gs - 1u) {
            unsigned oc = AADD(bs + 1024, 1u);
            CFENCE();
            if (oc == (idx + 1u) * 32u - 1u) {
                #pragma unroll
                for (unsigned gg = 0; gg < 32; ++gg)
                    STU(bs + 1056 + gg * 32, idx + 1u);
            }
        }
        CFENCE();
        while (LDU(bs + 1056 + g * 32) <= idx)
            __builtin_amdgcn_s_sleep(1);
        CFENCE();
    }
    __syncthreads();
}

// ============ single persistent cooperative kernel: p0+p1+diagonals+head ===
__global__ __launch_bounds__(256, 3) void k_all(
        const int* __restrict__ prem, const int* __restrict__ hyp,
        const float* __restrict__ emb, const float* __restrict__ Whh,
        const float* __restrict__ Wch, const float* __restrict__ Wcc,
        const float* __restrict__ Wih, const float* __restrict__ bih,
        const float* __restrict__ bhh,
        const float* __restrict__ bch, const float* __restrict__ bcc,
        const float* __restrict__ W1, const float* __restrict__ b1,
        const float* __restrict__ W2, const float* __restrict__ b2,
        const float* __restrict__ W3, const float* __restrict__ b3,
        float* __restrict__ outp, char* __restrict__ wsb) {
    __shared__ __align__(16) unsigned char smem[SMEMB];
    unsigned* flgA = (unsigned*)(wsb + OFF_FLG);
    unsigned* bs   = (unsigned*)(wsb + OFF_BAR2);
    const int grid = gridDim.x;
    const int gt = blockIdx.x * 256 + threadIdx.x;
    const int gstride = grid * 256;
    unsigned bidx = 0;

    // phase p0: weight pack + embedding gather
    p0_body(gt, gstride, prem, hyp, emb, Whh, Wch, Wcc, wsb);
    gbar(bs, bidx++, grid);
    // phase p1: Apre/Cpre pre-GEMMs (768 jobs)
    for (int job = blockIdx.x; job < 768; job += grid)
        p1_body(job, Wih, bih, bhh, wsb, smem);
    gbar(bs, bidx++, grid);

    // diagonal wavefront: one global barrier per diagonal; gates->cond
    // ordering within a diagonal via per-cell monotonic flags.
    for (int d = 0; d < P_ + H_ - 1; ++d) {
        int j_lo = (d > P_ - 1) ? d - (P_ - 1) : 0;
        int j_hi = (d < H_ - 1) ? d : H_ - 1;
        int ncells = j_hi - j_lo + 1;
        unsigned* flg = flgA + d * H_;
        for (int job = blockIdx.x; job < ncells * 32; job += grid)
            gates_job(d, ncells, j_lo, job, wsb, smem, flg);
        for (int job = blockIdx.x; job < ncells * 8; job += grid)
            cond_job(d, j_lo, job, bch, bcc, wsb, smem, flg);
        gbar(bs, bidx++, grid);
    }
    // MLP head
    const float* hfin = (const float*)(wsb + OFF_HF) + (size_t)(H_ - 1) * 32 * D_;
    float* T1 = (float*)(wsb + OFF_T1);
    float* T2 = (float*)(wsb + OFF_T2);
    if (blockIdx.x < 64) fc_job(hfin, W1, b1, T1, blockIdx.x, (float*)smem);
    gbar(bs, bidx++, grid);
    if (blockIdx.x < 64) fc_job(T1, W2, b2, T2, blockIdx.x, (float*)smem);
    gbar(bs, bidx++, grid);
    if (blockIdx.x == 0) sm_job(T2, W3, b3, outp, (float*)smem);
}

// ============ fallback per-phase kernels (kernel-boundary sync) ============
__global__ __launch_bounds__(256) void k_p0(
        const int* __restrict__ prem, const int* __restrict__ hyp,
        const float* __restrict__ emb, const float* __restrict__ Whh,
        const float* __restrict__ Wch, const float* __restrict__ Wcc,
        char* __restrict__ wsb) {
    p0_body(blockIdx.x * 256 + threadIdx.x, gridDim.x * 256,
            prem, hyp, emb, Whh, Wch, Wcc, wsb);
}

__global__ __launch_bounds__(256) void k_p1(
        const float* __restrict__ Wih, const float* __restrict__ bih,
        const float* __restrict__ bhh, char* __restrict__ wsb) {
    __shared__ __align__(16) unsigned char smem[SMEMB];
    p1_body(blockIdx.x, Wih, bih, bhh, wsb, smem);
}

__global__ __launch_bounds__(256, 3) void k_gates(int d, int ncells, char* __restrict__ wsb) {
    __shared__ __align__(16) unsigned char smem[SMEMD];
    int j_lo = (d > P_ - 1) ? d - (P_ - 1) : 0;
    gates_job(d, ncells, j_lo, blockIdx.x, wsb, smem,
              (unsigned*)(wsb + OFF_FLG) + d * H_);
}

__global__ __launch_bounds__(256, 3) void k_cond(
        int d, const float* __restrict__ bch, const float* __restrict__ bcc,
        char* __restrict__ wsb) {
    __shared__ __align__(16) unsigned char smem[64];
    int j_lo = (d > P_ - 1) ? d - (P_ - 1) : 0;
    cond_job(d, j_lo, blockIdx.x, bch, bcc, wsb, smem,
             (unsigned*)(wsb + OFF_FLG) + d * H_);
}

__global__ __launch_bounds__(256) void k_fc(
        const float* __restrict__ hin, const float* __restrict__ W,
        const float* __restrict__ bias, float* __restrict__ outv) {
    __shared__ float hsh[512];
    fc_job(hin, W, bias, outv, blockIdx.x, hsh);
}

__global__ __launch_bounds__(128) void k_sm(
        const float* __restrict__ T2, const float* __restrict__ W3,
        const float* __restrict__ b3, float* __restrict__ out) {
    __shared__ float lg[96];
    sm_job(T2, W3, b3, out, lg);
}

// ---------------------------------------------------------------------------
extern "C" void kernel_launch(void* const* d_in, const int* in_sizes, int n_in,
                              void* d_out, int out_size, void* d_ws, size_t ws_size,
                              hipStream_t stream) {
    (void)in_sizes; (void)n_in; (void)out_size; (void)ws_size;

    const int* prem = (const int*)d_in[0];
    const int* hyp  = (const int*)d_in[1];
    const float* emb = (const float*)d_in[2];
    const float* Wih = (const float*)d_in[3];
    const float* Whh = (const float*)d_in[4];
    const float* bih = (const float*)d_in[5];
    const float* bhh = (const float*)d_in[6];
    const float* Wch = (const float*)d_in[7];
    const float* bch = (const float*)d_in[8];
    const float* Wcc = (const float*)d_in[9];
    const float* bcc = (const float*)d_in[10];
    const float* W1  = (const float*)d_in[11];
    const float* b1  = (const float*)d_in[12];
    const float* W2  = (const float*)d_in[13];
    const float* b2  = (const float*)d_in[14];
    const float* W3  = (const float*)d_in[15];
    const float* b3  = (const float*)d_in[16];
    float* outp = (float*)d_out;
    char* wsb = (char*)d_ws;

    // zero flags + barrier state (monotonic counters, fresh each replay)
    (void)hipMemsetAsync(wsb + OFF_FLG, 0, ZERO_BYTES, stream);

    bool ok = false;
    {
        int maxb = 0;
        if (hipOccupancyMaxActiveBlocksPerMultiprocessor(
                &maxb, reinterpret_cast<const void*>(k_all), 256, 0) == hipSuccess &&
            maxb > 0) {
            int grid = (maxb >= 3) ? 768 : (maxb == 2 ? 512 : 256);
            void* args[] = {(void*)&prem, (void*)&hyp, (void*)&emb, (void*)&Whh,
                            (void*)&Wch, (void*)&Wcc, (void*)&Wih, (void*)&bih,
                            (void*)&bhh, (void*)&bch, (void*)&bcc,
                            (void*)&W1, (void*)&b1, (void*)&W2, (void*)&b2,
                            (void*)&W3, (void*)&b3, (void*)&outp, (void*)&wsb};
            ok = hipLaunchCooperativeKernel(reinterpret_cast<const void*>(k_all),
                                            dim3(grid), dim3(256), args, 0,
                                            stream) == hipSuccess;
        }
    }
    if (!ok) {
        // fallback: per-phase launches (kernel boundaries provide sync;
        // flags still give gates->cond order inside a diagonal pair)
        k_p0<<<512, 256, 0, stream>>>(prem, hyp, emb, Whh, Wch, Wcc, wsb);
        k_p1<<<768, 256, 0, stream>>>(Wih, bih, bhh, wsb);
        for (int d = 0; d < P_ + H_ - 1; ++d) {
            int j_lo = (d > P_ - 1) ? d - (P_ - 1) : 0;
            int j_hi = (d < H_ - 1) ? d : H_ - 1;
            int ncells = j_hi - j_lo + 1;
            k_gates<<<ncells * 32, 256, 0, stream>>>(d, ncells, wsb);
            k_cond<<<ncells * 8, 256, 0, stream>>>(d, bch, bcc, wsb);
        }
        float* T1 = (float*)(wsb + OFF_T1);
        float* T2 = (float*)(wsb + OFF_T2);
        const float* hfin = (const float*)(wsb + OFF_HF) + (size_t)(H_ - 1) * 32 * D_;
        k_fc<<<64, 256, 0, stream>>>(hfin, W1, b1, T1);
        k_fc<<<64, 256, 0, stream>>>(T1, W2, b2, T2);
        k_sm<<<1, 128, 0, stream>>>(T2, W3, b3, outp);
    }
}

// Round 7
// 2101.559 us; speedup vs baseline: 1.8238x; 1.8238x over previous
//
#include <hip/hip_runtime.h>

#define P_   24
#define H_   24
#define E_   300
#define D_   512
#define TWOD 1024
#define G4   4096
#define SMEMB  27648
#define BUFSZ  23040            // A(32x72x2=4608) + B(128x72x2=18432)
#define SMEMG2 46080            // two buffers

typedef __attribute__((ext_vector_type(8))) short bf16x8;
typedef __attribute__((ext_vector_type(4))) float f32x4;

__device__ __forceinline__ float bflo(unsigned w) { return __uint_as_float(w << 16); }
__device__ __forceinline__ float bfhi(unsigned w) { return __uint_as_float(w & 0xffff0000u); }
__device__ __forceinline__ unsigned short f2bf(float f) {
    unsigned int x = __float_as_uint(f);
    unsigned int r = (x + 0x7fffu + ((x >> 16) & 1u)) >> 16;
    return (unsigned short)r;
}
__device__ __forceinline__ float sigf(float x) {
    return 1.0f / (1.0f + __expf(-x));
}
__device__ __forceinline__ float tanh_f(float x) {
    return 2.0f / (1.0f + __expf(-2.0f * x)) - 1.0f;
}

// fabric-coherent relaxed agent-scope accessors (HW-coherent across XCDs,
// L2-allocating). NO acquire/release anywhere in the hot loop (agent-acquire
// => buffer_inv kills warm L2). Ordering: __syncthreads vmcnt drain
// (producer) / barrier-then-load (consumer). CFENCE pins compiler placement.
#define CFENCE() asm volatile("" ::: "memory")
#define LD8(p)   __hip_atomic_load((const unsigned long long*)(p), __ATOMIC_RELAXED, __HIP_MEMORY_SCOPE_AGENT)
#define LDF(p)   __hip_atomic_load((const float*)(p), __ATOMIC_RELAXED, __HIP_MEMORY_SCOPE_AGENT)
#define LDU(p)   __hip_atomic_load((const unsigned*)(p), __ATOMIC_RELAXED, __HIP_MEMORY_SCOPE_AGENT)
#define STU(p,v) __hip_atomic_store((unsigned*)(p), (unsigned)(v), __ATOMIC_RELAXED, __HIP_MEMORY_SCOPE_AGENT)
#define STF(p,v) __hip_atomic_store((float*)(p), (float)(v), __ATOMIC_RELAXED, __HIP_MEMORY_SCOPE_AGENT)
#define AADD(p,v) __hip_atomic_fetch_add((unsigned*)(p), (unsigned)(v), __ATOMIC_RELAXED, __HIP_MEMORY_SCOPE_AGENT)

// ---------------- workspace byte offsets ----------------
// Apre/Cpre TRANSPOSED: [nt=32][row=768][gate=4][u=32] bf16 (6.29 MB each).
// Gates job (cell,nt) reads its nt-slice only -> per-XCD working set
// = 4 nt-slices x 2 arrays = 1.6 MB, L2-resident across all 47 diagonals.
#define OFF_WHHP 0u           // packed Whh bf16: [nt=32][q=4][u=32][k=1024]
#define OFF_WCHB 8388608u     // 512*1024 bf16
#define OFF_WCCB 9437184u     // 512*1024 bf16
#define OFF_APRE 10485760u    // transposed, 6.29MB
#define OFF_CPRE 16777216u    // transposed, 6.29MB
#define OFF_PX   23068672u    // 768*320 bf16
#define OFF_HX   23560192u    // 768*320 bf16
#define OFF_HBB  24051712u    // 2*24*32*512 bf16 (h state, parity buffers)
#define OFF_CBF  25624576u    // 2*24*32*512 f32  (c state)
#define OFF_H2B  28770304u    // 24*32*1024 bf16
#define OFF_C2B  30343168u    // 24*32*1024 bf16
#define OFF_HF   31916032u    // 24*32*512 f32 (final h for MLP)
#define OFF_T1   33488896u    // 32*512 f32
#define OFF_T2   33554432u    // 32*512 f32
// barrier state: 32 group counter lines (g*32 u32), central (u32 1024),
// 32 group generation lines (u32 1056 + g*32). Monotonic; zeroed by k_p0.
#define OFF_BAR2 33619968u

// ============ P0: weight convert/pack + embedding gather (grid 512) ========
__global__ __launch_bounds__(256) void k_p0(
        const int* __restrict__ prem, const int* __restrict__ hyp,
        const float* __restrict__ emb, const float* __restrict__ Whh,
        const float* __restrict__ Wch, const float* __restrict__ Wcc,
        char* __restrict__ wsb) {
    unsigned short* WhhP = (unsigned short*)(wsb + OFF_WHHP);
    unsigned short* WchB = (unsigned short*)(wsb + OFF_WCHB);
    unsigned short* WccB = (unsigned short*)(wsb + OFF_WCCB);
    unsigned short* PX   = (unsigned short*)(wsb + OFF_PX);
    unsigned short* HX   = (unsigned short*)(wsb + OFF_HX);

    int gt = blockIdx.x * 256 + threadIdx.x;
    int stride = gridDim.x * 256;
    // zero barrier state via fabric stores (visible to k_loop's fabric atomics)
    if (gt < 2560) STU(&((unsigned*)(wsb + OFF_BAR2))[gt], 0u);
    // Whh: convert + permute rows n=q*1024+nt*32+u -> pr=nt*128+q*32+u
    for (int idx = gt; idx < 524288; idx += stride) {
        int n = idx >> 7;              // original row
        int k8 = (idx & 127) * 8;      // col start
        int q = n >> 10, rest = n & 1023;
        int nt = rest >> 5, u = rest & 31;
        int pr = nt * 128 + q * 32 + u;
        const float* s = Whh + (size_t)n * TWOD + k8;
        float4 va = *(const float4*)s, vb = *(const float4*)(s + 4);
        unsigned short o[8] = {f2bf(va.x), f2bf(va.y), f2bf(va.z), f2bf(va.w),
                               f2bf(vb.x), f2bf(vb.y), f2bf(vb.z), f2bf(vb.w)};
        *(uint4*)(WhhP + (size_t)pr * TWOD + k8) = *(const uint4*)o;
    }
    for (int idx = gt; idx < 131072; idx += stride) {
        int cc = idx & 65535;
        const float* s = ((idx < 65536) ? Wch : Wcc) + (size_t)cc * 8;
        unsigned short* dp = ((idx < 65536) ? WchB : WccB) + (size_t)cc * 8;
        float4 va = *(const float4*)s, vb = *(const float4*)(s + 4);
        unsigned short o[8] = {f2bf(va.x), f2bf(va.y), f2bf(va.z), f2bf(va.w),
                               f2bf(vb.x), f2bf(vb.y), f2bf(vb.z), f2bf(vb.w)};
        *(uint4*)dp = *(const uint4*)o;
    }
    for (int idx = gt; idx < 61440; idx += stride) {
        int isH = idx >= 30720 ? 1 : 0;
        int id2 = idx - isH * 30720;
        int rb = id2 / 40, c8 = (id2 % 40) * 8;
        int ri = rb >> 5, rbb = rb & 31;
        int tok = isH ? hyp[rbb * H_ + ri] : prem[rbb * P_ + ri];
        const float* s = emb + (size_t)tok * E_ + c8;
        unsigned short o[8];
        for (int e = 0; e < 8; ++e)
            o[e] = (c8 + e < E_) ? f2bf(s[e]) : (unsigned short)0;
        *(uint4*)((isH ? HX : PX) + rb * 320 + c8) = *(const uint4*)o;
    }
}

// ============ P1: Apre/Cpre GEMM, 64x128 tiles, K=320 (grid 768) ===========
// Writes TRANSPOSED layout [knt][row][g][u]; plain cached stores (flushed at
// launch boundary before k_loop reads them).
__global__ __launch_bounds__(256) void k_p1(
        const float* __restrict__ Wih, const float* __restrict__ bih,
        const float* __restrict__ bhh, char* __restrict__ wsb) {
    const unsigned short* PX = (const unsigned short*)(wsb + OFF_PX);
    const unsigned short* HX = (const unsigned short*)(wsb + OFF_HX);
    unsigned short* Apre = (unsigned short*)(wsb + OFF_APRE);
    unsigned short* Cpre = (unsigned short*)(wsb + OFF_CPRE);

    __shared__ __align__(16) unsigned char smem[SMEMB];
    const int t = threadIdx.x;
    const int lane = t & 63, wvi = t >> 6, l16 = lane & 15, quad = lane >> 4;
    const int wm = wvi >> 1, wn = wvi & 1;
    unsigned short (*At)[72] = (unsigned short (*)[72])smem;            // 64 rows
    unsigned short (*Bt)[72] = (unsigned short (*)[72])(smem + 9216);   // 128 rows

    int q = blockIdx.x;
    int x = q & 7, slot = q >> 3;
    int z = slot / 48, rem = slot % 48;
    int ntg = rem / 12, mt = rem % 12;
    int nt = ntg * 8 + x;
    const unsigned short* X = z ? HX : PX;
    int koff = z ? E_ : 0;
    unsigned short* Out = z ? Cpre : Apre;
    f32x4 acc[2][4] = {};
    int arow = t >> 2, acol = (t & 3) * 16;
    int brow = t >> 1, bcol = (t & 1) * 32;
    for (int s = 0; s < 5; ++s) {
        int k0 = s * 64;
        {
            const uint4* src = (const uint4*)(X + (size_t)(mt * 64 + arow) * 320 + k0 + acol);
            uint4* dst = (uint4*)&At[arow][acol];
            dst[0] = src[0]; dst[1] = src[1];
        }
        {
            int n = nt * 128 + brow;
            const float* wrow = Wih + (size_t)n * (2 * E_) + koff;
            unsigned short* dst = &Bt[brow][bcol];
            for (int c4 = 0; c4 < 8; ++c4) {
                int k = k0 + bcol + c4 * 4;
                if (k < E_) {
                    float4 v = *(const float4*)(wrow + k);
                    dst[c4 * 4 + 0] = f2bf(v.x); dst[c4 * 4 + 1] = f2bf(v.y);
                    dst[c4 * 4 + 2] = f2bf(v.z); dst[c4 * 4 + 3] = f2bf(v.w);
                } else {
                    dst[c4 * 4 + 0] = 0; dst[c4 * 4 + 1] = 0;
                    dst[c4 * 4 + 2] = 0; dst[c4 * 4 + 3] = 0;
                }
            }
        }
        __syncthreads();
        for (int ks = 0; ks < 2; ++ks) {
            bf16x8 a[2], bb[4];
            for (int mi = 0; mi < 2; ++mi)
                a[mi] = *(const bf16x8*)&At[wm * 32 + mi * 16 + l16][ks * 32 + quad * 8];
            for (int ni = 0; ni < 4; ++ni)
                bb[ni] = *(const bf16x8*)&Bt[wn * 64 + ni * 16 + l16][ks * 32 + quad * 8];
            for (int mi = 0; mi < 2; ++mi)
                for (int ni = 0; ni < 4; ++ni)
                    acc[mi][ni] = __builtin_amdgcn_mfma_f32_16x16x32_bf16(
                        a[mi], bb[ni], acc[mi][ni], 0, 0, 0);
        }
        __syncthreads();
    }
    for (int mi = 0; mi < 2; ++mi) {
        int rbase = mt * 64 + wm * 32 + mi * 16 + quad * 4;
        for (int ni = 0; ni < 4; ++ni) {
            int n = nt * 128 + wn * 64 + ni * 16 + l16;   // [0,4096) gate-major
            int g = n >> 10, cc = n & 1023;
            int knt = cc >> 5, u = cc & 31;
            float bias = z ? 0.0f : (bih[n] + bhh[n]);
            for (int r = 0; r < 4; ++r) {
                size_t ta = (((size_t)knt * 768 + (rbase + r)) * 4 + g) * 32 + u;
                Out[ta] = f2bf(acc[mi][ni][r] + bias);
            }
        }
    }
}

// ====== gates job body: job=(cell,nt), 32x128 tile, K=1024, dbuf LDS =======
// A operand (prev-diagonal h state) via fabric loads; B (Whh slice) plain
// cached (XCD-pinned, L2-resident). Epilogue reads TRANSPOSED Apre/Cpre:
// contiguous 256B per row from the XCD-local L2-resident nt-slice.
__device__ __forceinline__ void gates_job(
        int d, int ncells, int j_lo, int job,
        char* __restrict__ wsb, unsigned char* smem) {
    const unsigned short* WhhP = (const unsigned short*)(wsb + OFF_WHHP);
    const unsigned short* Apre = (const unsigned short*)(wsb + OFF_APRE);
    const unsigned short* Cpre = (const unsigned short*)(wsb + OFF_CPRE);
    const unsigned short* HbB  = (const unsigned short*)(wsb + OFF_HBB);
    const float*          Cbf  = (const float*)(wsb + OFF_CBF);
    unsigned short* H2B = (unsigned short*)(wsb + OFF_H2B);
    unsigned short* C2B = (unsigned short*)(wsb + OFF_C2B);

    int x = job & 7, slot = job >> 3;
    int ntg = slot / ncells, c = slot - ntg * ncells;
    int nt = ntg * 8 + x;
    int cj = j_lo + c, ci = d - cj;

    const unsigned short* HpB = HbB + (size_t)((d + 1) & 1) * (H_ * 32 * D_);
    const float* Cp = Cbf + (size_t)((d + 1) & 1) * (H_ * 32 * D_);

    const int t = threadIdx.x;
    const int lane = t & 63, wvi = t >> 6, l16 = lane & 15, quad = lane >> 4;

    f32x4 acc[2][2] = {};
    const int arow = t >> 3, acol = (t & 7) * 8;   // 16 B/thread A stage
    const int brow = t >> 1, bcol = (t & 1) * 32;  // 64 B/thread B stage
    const unsigned short* wsrc = WhhP + (size_t)(nt * 128 + brow) * TWOD + bcol;
    const unsigned short* asrcL =
        (ci > 0) ? HpB + (size_t)(cj * 32 + arow) * D_ : nullptr;
    const unsigned short* asrcD =
        (cj > 0) ? HpB + (size_t)((cj - 1) * 32 + arow) * D_ : nullptr;

    // prefetch entire A operand (16 steps x 16 B) via fabric loads
    uint4 aPre[16];
    #pragma unroll
    for (int s = 0; s < 16; ++s) {
        int kk = s * 64 + acol;
        const unsigned short* sp =
            (kk < D_) ? (asrcL ? asrcL + kk : nullptr)
                      : (asrcD ? asrcD + (kk - D_) : nullptr);
        if (sp) {
            unsigned long long x0 = LD8(sp), x1 = LD8(sp + 4);
            aPre[s].x = (unsigned)x0; aPre[s].y = (unsigned)(x0 >> 32);
            aPre[s].z = (unsigned)x1; aPre[s].w = (unsigned)(x1 >> 32);
        } else {
            aPre[s].x = 0u; aPre[s].y = 0u; aPre[s].z = 0u; aPre[s].w = 0u;
        }
    }

    uint4 bR0, bR1, bR2, bR3;
    #define LOADB(s_) do {                                                     \
            const uint4* s4 = (const uint4*)(wsrc + (s_) * 64);                \
            bR0 = s4[0]; bR1 = s4[1]; bR2 = s4[2]; bR3 = s4[3];                \
        } while (0)
    #define STORE_STEP(p_, s_) do {                                            \
            unsigned short (*At_)[72] = (unsigned short (*)[72])(smem + (p_) * BUFSZ); \
            unsigned short (*Bt_)[72] = (unsigned short (*)[72])(smem + (p_) * BUFSZ + 4608); \
            *(uint4*)&At_[arow][acol] = aPre[s_];                              \
            uint4* dp = (uint4*)&Bt_[brow][bcol];                              \
            dp[0] = bR0; dp[1] = bR1; dp[2] = bR2; dp[3] = bR3;                \
        } while (0)

    LOADB(0);
    STORE_STEP(0, 0);
    __syncthreads();
    #pragma unroll
    for (int s = 0; s < 16; ++s) {
        if (s < 15) LOADB(s + 1);
        int p = s & 1;
        unsigned short (*At)[72] = (unsigned short (*)[72])(smem + p * BUFSZ);
        unsigned short (*Bt)[72] = (unsigned short (*)[72])(smem + p * BUFSZ + 4608);
        for (int ks = 0; ks < 2; ++ks) {
            bf16x8 a0 = *(const bf16x8*)&At[l16][ks * 32 + quad * 8];
            bf16x8 a1 = *(const bf16x8*)&At[16 + l16][ks * 32 + quad * 8];
            bf16x8 b0 = *(const bf16x8*)&Bt[wvi * 32 + l16][ks * 32 + quad * 8];
            bf16x8 b1 = *(const bf16x8*)&Bt[wvi * 32 + 16 + l16][ks * 32 + quad * 8];
            acc[0][0] = __builtin_amdgcn_mfma_f32_16x16x32_bf16(a0, b0, acc[0][0], 0, 0, 0);
            acc[0][1] = __builtin_amdgcn_mfma_f32_16x16x32_bf16(a0, b1, acc[0][1], 0, 0, 0);
            acc[1][0] = __builtin_amdgcn_mfma_f32_16x16x32_bf16(a1, b0, acc[1][0], 0, 0, 0);
            acc[1][1] = __builtin_amdgcn_mfma_f32_16x16x32_bf16(a1, b1, acc[1][1], 0, 0, 0);
        }
        if (s < 15) {
            STORE_STEP(1 - p, s + 1);
            __syncthreads();
        }
    }
    #undef LOADB
    #undef STORE_STEP

    // epilogue: acc -> LDS (aliases buf0; buf0 reads ended before s=15's sync,
    // buf1 region is disjoint) -> fused LSTM activation
    float* Dt = (float*)smem;   // [32][132]
    for (int mi = 0; mi < 2; ++mi)
        for (int ni = 0; ni < 2; ++ni) {
            int cc2 = wvi * 32 + ni * 16 + l16;
            int rr = mi * 16 + quad * 4;
            for (int r = 0; r < 4; ++r)
                Dt[(rr + r) * 132 + cc2] = acc[mi][ni][r];
        }
    __syncthreads();
    {
        int u2 = (t & 15) * 2, r0 = (t >> 4) * 2;
        int k = nt * 32 + u2;            // even -> 4B-aligned pairs
        for (int r = r0; r < r0 + 2; ++r) {
            // transposed [nt][row][g][u]: contiguous 256B per row, L2-local
            size_t abase = (((size_t)nt * 768 + (ci * 32 + r)) * 4) * 32 + u2;
            size_t cbase = (((size_t)nt * 768 + (cj * 32 + r)) * 4) * 32 + u2;
            unsigned ap0 = *(const unsigned*)&Apre[abase];
            unsigned ap1 = *(const unsigned*)&Apre[abase + 32];
            unsigned ap2 = *(const unsigned*)&Apre[abase + 64];
            unsigned ap3 = *(const unsigned*)&Apre[abase + 96];
            unsigned cp0 = *(const unsigned*)&Cpre[cbase];
            unsigned cp1 = *(const unsigned*)&Cpre[cbase + 32];
            unsigned cp2 = *(const unsigned*)&Cpre[cbase + 64];
            unsigned cp3 = *(const unsigned*)&Cpre[cbase + 96];
            float ccat0, ccat1;
            if (k < D_) {
                if (ci > 0) {
                    const float* cp = Cp + (size_t)(cj * 32 + r) * D_ + k;
                    ccat0 = LDF(cp); ccat1 = LDF(cp + 1);
                } else { ccat0 = 0.0f; ccat1 = 0.0f; }
            } else {
                if (cj > 0) {
                    const float* cp = Cp + (size_t)((cj - 1) * 32 + r) * D_ + (k - D_);
                    ccat0 = LDF(cp); ccat1 = LDF(cp + 1);
                } else { ccat0 = 0.0f; ccat1 = 0.0f; }
            }
            float g00 = Dt[r * 132 +      u2]     + bflo(ap0) + bflo(cp0);
            float g01 = Dt[r * 132 +      u2 + 1] + bfhi(ap0) + bfhi(cp0);
            float g10 = Dt[r * 132 + 32 + u2]     + bflo(ap1) + bflo(cp1);
            float g11 = Dt[r * 132 + 32 + u2 + 1] + bfhi(ap1) + bfhi(cp1);
            float g20 = Dt[r * 132 + 64 + u2]     + bflo(ap2) + bflo(cp2);
            float g21 = Dt[r * 132 + 64 + u2 + 1] + bfhi(ap2) + bfhi(cp2);
            float g30 = Dt[r * 132 + 96 + u2]     + bflo(ap3) + bflo(cp3);
            float g31 = Dt[r * 132 + 96 + u2 + 1] + bfhi(ap3) + bfhi(cp3);
            float c20 = sigf(g10) * ccat0 + sigf(g00) * tanh_f(g20);
            float h20 = sigf(g30) * tanh_f(c20);
            float c21 = sigf(g11) * ccat1 + sigf(g01) * tanh_f(g21);
            float h21 = sigf(g31) * tanh_f(c21);
            unsigned hw = (unsigned)f2bf(h20) | ((unsigned)f2bf(h21) << 16);
            unsigned cw = (unsigned)f2bf(c20) | ((unsigned)f2bf(c21) << 16);
            STU(&H2B[(size_t)(c * 32 + r) * TWOD + k], hw);
            STU(&C2B[(size_t)(c * 32 + r) * TWOD + k], cw);
        }
    }
    // protect Dt (aliases buf0) before caller reuses smem for the next job
    __syncthreads();
}

// ====== cond job body: job=(cell, z,ntile), 32x128 tile, K=1024, dbuf ======
__device__ __forceinline__ void cond_job(
        int d, int j_lo, int job,
        const float* __restrict__ bch, const float* __restrict__ bcc,
        char* __restrict__ wsb, unsigned char* smem) {
    const unsigned short* H2B  = (const unsigned short*)(wsb + OFF_H2B);
    const unsigned short* C2B  = (const unsigned short*)(wsb + OFF_C2B);
    const unsigned short* WchB = (const unsigned short*)(wsb + OFF_WCHB);
    const unsigned short* WccB = (const unsigned short*)(wsb + OFF_WCCB);
    unsigned short* HbB = (unsigned short*)(wsb + OFF_HBB);
    float* Cbf = (float*)(wsb + OFF_CBF);
    float* Hf  = (float*)(wsb + OFF_HF);

    int xcd = job & 7, c = job >> 3;
    int z = xcd >> 2, ntile = xcd & 3;
    const unsigned short* Ain = z ? C2B : H2B;
    const unsigned short* W = z ? WccB : WchB;
    int cj = j_lo + c;

    const int t = threadIdx.x;
    const int lane = t & 63, wvi = t >> 6, l16 = lane & 15, quad = lane >> 4;

    unsigned short* HbC = HbB + (size_t)(d & 1) * (H_ * 32 * D_);
    float* CbC = Cbf + (size_t)(d & 1) * (H_ * 32 * D_);

    f32x4 acc[2][2] = {};
    const int arow = t >> 3, acol = (t & 7) * 8;
    const int brow = t >> 1, bcol = (t & 1) * 32;
    const unsigned short* asrc = Ain + (size_t)(c * 32 + arow) * TWOD + acol;
    const unsigned short* wsrc = W + (size_t)(ntile * 128 + brow) * TWOD + bcol;

    // prefetch entire A operand via fabric loads
    uint4 aPre[16];
    #pragma unroll
    for (int s = 0; s < 16; ++s) {
        unsigned long long x0 = LD8(asrc + s * 64), x1 = LD8(asrc + s * 64 + 4);
        aPre[s].x = (unsigned)x0; aPre[s].y = (unsigned)(x0 >> 32);
        aPre[s].z = (unsigned)x1; aPre[s].w = (unsigned)(x1 >> 32);
    }

    uint4 bR0, bR1, bR2, bR3;
    #define LOADB(s_) do {                                                     \
            const uint4* s4 = (const uint4*)(wsrc + (s_) * 64);                \
            bR0 = s4[0]; bR1 = s4[1]; bR2 = s4[2]; bR3 = s4[3];                \
        } while (0)
    #define STORE_STEP(p_, s_) do {                                            \
            unsigned short (*At_)[72] = (unsigned short (*)[72])(smem + (p_) * BUFSZ); \
            unsigned short (*Bt_)[72] = (unsigned short (*)[72])(smem + (p_) * BUFSZ + 4608); \
            *(uint4*)&At_[arow][acol] = aPre[s_];                              \
            uint4* dp = (uint4*)&Bt_[brow][bcol];                              \
            dp[0] = bR0; dp[1] = bR1; dp[2] = bR2; dp[3] = bR3;                \
        } while (0)

    LOADB(0);
    STORE_STEP(0, 0);
    __syncthreads();
    #pragma unroll
    for (int s = 0; s < 16; ++s) {
        if (s < 15) LOADB(s + 1);
        int p = s & 1;
        unsigned short (*At)[72] = (unsigned short (*)[72])(smem + p * BUFSZ);
        unsigned short (*Bt)[72] = (unsigned short (*)[72])(smem + p * BUFSZ + 4608);
        for (int ks = 0; ks < 2; ++ks) {
            bf16x8 a0 = *(const bf16x8*)&At[l16][ks * 32 + quad * 8];
            bf16x8 a1 = *(const bf16x8*)&At[16 + l16][ks * 32 + quad * 8];
            bf16x8 b0 = *(const bf16x8*)&Bt[wvi * 32 + l16][ks * 32 + quad * 8];
            bf16x8 b1 = *(const bf16x8*)&Bt[wvi * 32 + 16 + l16][ks * 32 + quad * 8];
            acc[0][0] = __builtin_amdgcn_mfma_f32_16x16x32_bf16(a0, b0, acc[0][0], 0, 0, 0);
            acc[0][1] = __builtin_amdgcn_mfma_f32_16x16x32_bf16(a0, b1, acc[0][1], 0, 0, 0);
            acc[1][0] = __builtin_amdgcn_mfma_f32_16x16x32_bf16(a1, b0, acc[1][0], 0, 0, 0);
            acc[1][1] = __builtin_amdgcn_mfma_f32_16x16x32_bf16(a1, b1, acc[1][1], 0, 0, 0);
        }
        if (s < 15) {
            STORE_STEP(1 - p, s + 1);
            __syncthreads();
        }
    }
    #undef LOADB
    #undef STORE_STEP

    for (int mi = 0; mi < 2; ++mi) {
        int rr = mi * 16 + quad * 4;
        for (int ni = 0; ni < 2; ++ni) {
            int n = ntile * 128 + wvi * 32 + ni * 16 + l16;
            float bsv = z ? bcc[n] : bch[n];
            for (int r = 0; r < 4; ++r) {
                int rb = rr + r;
                float val = acc[mi][ni][r] + bsv;
                if (z) {
                    STF(&CbC[(size_t)(cj * 32 + rb) * D_ + n], val);
                } else {
                    // pack adjacent columns (lanes l16 even/odd) into one u32
                    float pv = __shfl_xor(val, 1);
                    if ((lane & 1) == 0) {
                        unsigned w2 = (unsigned)f2bf(val) | ((unsigned)f2bf(pv) << 16);
                        STU(&HbC[(size_t)(cj * 32 + rb) * D_ + n], w2);
                    }
                    if (d == P_ + H_ - 2)
                        STF(&Hf[(size_t)(cj * 32 + rb) * D_ + n], val);
                }
            }
        }
    }
    // no trailing LDS reads; next job's STORE_STEP(0,0) is ordered by its
    // own __syncthreads.
}

// ============ MLP head job bodies ==========================================
__device__ __forceinline__ void fc_job(
        const float* __restrict__ hin, const float* __restrict__ W,
        const float* __restrict__ bias, float* __restrict__ outv, int job,
        float* hsh) {
    int t = threadIdx.x;
    int row = job >> 1, cb = (job & 1) * 256;
    const float* h = hin + (size_t)row * D_;
    hsh[t * 2]     = LDF(h + t * 2);
    hsh[t * 2 + 1] = LDF(h + t * 2 + 1);
    __syncthreads();
    int col = cb + t;
    const float* w = W + (size_t)col * D_;
    float accv = bias[col];
    for (int k = 0; k < D_; k += 4) {
        float4 wv4 = *(const float4*)(w + k);
        float4 hv = *(const float4*)(hsh + k);
        accv += hv.x * wv4.x + hv.y * wv4.y + hv.z * wv4.z + hv.w * wv4.w;
    }
    STF(&outv[(size_t)row * D_ + col], fmaxf(accv, 0.0f));
    __syncthreads();
}

__device__ __forceinline__ void sm_job(
        const float* __restrict__ T2, const float* __restrict__ W3,
        const float* __restrict__ b3, float* __restrict__ out, float* lg) {
    int t = threadIdx.x;
    if (t < 96) {
        int rb = t / 3, cls = t % 3;
        const float* h = T2 + (size_t)rb * D_;
        const float* w = W3 + (size_t)cls * D_;
        float accv = b3[cls];
        for (int k = 0; k < D_; k += 4) {
            float4 wv4 = *(const float4*)(w + k);
            accv += LDF(h + k) * wv4.x + LDF(h + k + 1) * wv4.y +
                    LDF(h + k + 2) * wv4.z + LDF(h + k + 3) * wv4.w;
        }
        lg[rb * 3 + cls] = accv;
    }
    __syncthreads();
    if (t < 32) {
        float a = lg[t * 3 + 0], bq = lg[t * 3 + 1], cq = lg[t * 3 + 2];
        float m = fmaxf(a, fmaxf(bq, cq));
        float ea = __expf(a - m), eb = __expf(bq - m), ec = __expf(cq - m);
        float s = 1.0f / (ea + eb + ec);
        out[t * 3 + 0] = ea * s;
        out[t * 3 + 1] = eb * s;
        out[t * 3 + 2] = ec * s;
    }
}

// ============ lightweight monotonic 2-level grid barrier ===================
// No acquire/release (no L2 inv/wb). 32 arrival groups; monotonic counters;
// zeroed by k_p0 each run.
__device__ __forceinline__ void gbar(unsigned* bs, unsigned idx, int grid) {
    __syncthreads();      // drains each wave's outstanding (fabric) stores
    if (threadIdx.x == 0) {
        unsigned g = blockIdx.x & 31u;
        unsigned gs = (unsigned)grid >> 5;
        CFENCE();
        unsigned old = AADD(bs + g * 32, 1u);
        CFENCE();
        if (old == (idx + 1u) * gs - 1u) {
            unsigned oc = AADD(bs + 1024, 1u);
            CFENCE();
            if (oc == (idx + 1u) * 32u - 1u) {
                #pragma unroll
                for (unsigned gg = 0; gg < 32; ++gg)
                    STU(bs + 1056 + gg * 32, idx + 1u);
            }
        }
        CFENCE();
        while (LDU(bs + 1056 + g * 32) <= idx)
            __builtin_amdgcn_s_sleep(2);
        CFENCE();
    }
    __syncthreads();
}

// ============ persistent cooperative kernel: all 47 diagonals + head =======
__global__ __launch_bounds__(256, 3) void k_loop(
        const float* __restrict__ bch, const float* __restrict__ bcc,
        const float* __restrict__ W1, const float* __restrict__ b1,
        const float* __restrict__ W2, const float* __restrict__ b2,
        const float* __restrict__ W3, const float* __restrict__ b3,
        float* __restrict__ outp, char* __restrict__ wsb) {
    __shared__ __align__(16) unsigned char smem[SMEMG2];
    unsigned* bs = (unsigned*)(wsb + OFF_BAR2);
    const int grid = gridDim.x;
    unsigned bidx = 0;
    for (int d = 0; d < P_ + H_ - 1; ++d) {
        int j_lo = (d > P_ - 1) ? d - (P_ - 1) : 0;
        int j_hi = (d < H_ - 1) ? d : H_ - 1;
        int ncells = j_hi - j_lo + 1;
        for (int job = blockIdx.x; job < ncells * 32; job += grid)
            gates_job(d, ncells, j_lo, job, wsb, smem);
        gbar(bs, bidx++, grid);
        for (int job = blockIdx.x; job < ncells * 8; job += grid)
            cond_job(d, j_lo, job, bch, bcc, wsb, smem);
        gbar(bs, bidx++, grid);
    }
    // MLP head folded in
    const float* hfin = (const float*)(wsb + OFF_HF) + (size_t)(H_ - 1) * 32 * D_;
    float* T1 = (float*)(wsb + OFF_T1);
    float* T2 = (float*)(wsb + OFF_T2);
    if (blockIdx.x < 64) fc_job(hfin, W1, b1, T1, blockIdx.x, (float*)smem);
    gbar(bs, bidx++, grid);
    if (blockIdx.x < 64) fc_job(T1, W2, b2, T2, blockIdx.x, (float*)smem);
    gbar(bs, bidx++, grid);
    if (blockIdx.x == 0) sm_job(T2, W3, b3, outp, (float*)smem);
}

// ============ fallback per-diagonal kernels (kernel-boundary sync) =========
__global__ __launch_bounds__(256, 3) void k_gates(int d, int ncells, char* __restrict__ wsb) {
    __shared__ __align__(16) unsigned char smem[SMEMG2];
    int j_lo = (d > P_ - 1) ? d - (P_ - 1) : 0;
    gates_job(d, ncells, j_lo, blockIdx.x, wsb, smem);
}

__global__ __launch_bounds__(256, 3) void k_cond(
        int d, const float* __restrict__ bch, const float* __restrict__ bcc,
        char* __restrict__ wsb) {
    __shared__ __align__(16) unsigned char smem[SMEMG2];
    int j_lo = (d > P_ - 1) ? d - (P_ - 1) : 0;
    cond_job(d, j_lo, blockIdx.x, bch, bcc, wsb, smem);
}

__global__ __launch_bounds__(256) void k_fc(
        const float* __restrict__ hin, const float* __restrict__ W,
        const float* __restrict__ bias, float* __restrict__ outv) {
    __shared__ float hsh[512];
    fc_job(hin, W, bias, outv, blockIdx.x, hsh);
}

__global__ __launch_bounds__(128) void k_sm(
        const float* __restrict__ T2, const float* __restrict__ W3,
        const float* __restrict__ b3, float* __restrict__ out) {
    __shared__ float lg[96];
    sm_job(T2, W3, b3, out, lg);
}

// ---------------------------------------------------------------------------
extern "C" void kernel_launch(void* const* d_in, const int* in_sizes, int n_in,
                              void* d_out, int out_size, void* d_ws, size_t ws_size,
                              hipStream_t stream) {
    (void)in_sizes; (void)n_in; (void)out_size; (void)ws_size;

    const int* prem = (const int*)d_in[0];
    const int* hyp  = (const int*)d_in[1];
    const float* emb = (const float*)d_in[2];
    const float* Wih = (const float*)d_in[3];
    const float* Whh = (const float*)d_in[4];
    const float* bih = (const float*)d_in[5];
    const float* bhh = (const float*)d_in[6];
    const float* Wch = (const float*)d_in[7];
    const float* bch = (const float*)d_in[8];
    const float* Wcc = (const float*)d_in[9];
    const float* bcc = (const float*)d_in[10];
    const float* W1  = (const float*)d_in[11];
    const float* b1  = (const float*)d_in[12];
    const float* W2  = (const float*)d_in[13];
    const float* b2  = (const float*)d_in[14];
    const float* W3  = (const float*)d_in[15];
    const float* b3  = (const float*)d_in[16];
    float* outp = (float*)d_out;
    char* wsb = (char*)d_ws;

    k_p0<<<512, 256, 0, stream>>>(prem, hyp, emb, Whh, Wch, Wcc, wsb);
    k_p1<<<768, 256, 0, stream>>>(Wih, bih, bhh, wsb);

    // persistent cooperative diagonal loop; grid sized to validated occupancy
    bool ok = false;
    {
        int maxb = 0;
        if (hipOccupancyMaxActiveBlocksPerMultiprocessor(
                &maxb, reinterpret_cast<const void*>(k_loop), 256, 0) == hipSuccess &&
            maxb > 0) {
            int grid = (maxb >= 3) ? 768 : (maxb == 2 ? 512 : 256);
            void* args[] = {(void*)&bch, (void*)&bcc, (void*)&W1, (void*)&b1,
                            (void*)&W2,  (void*)&b2,  (void*)&W3, (void*)&b3,
                            (void*)&outp, (void*)&wsb};
            ok = hipLaunchCooperativeKernel(reinterpret_cast<const void*>(k_loop),
                                            dim3(grid), dim3(256), args, 0,
                                            stream) == hipSuccess;
        }
    }
    if (!ok) {
        // fallback: per-diagonal launches (kernel boundaries provide sync)
        for (int d = 0; d < P_ + H_ - 1; ++d) {
            int j_lo = (d > P_ - 1) ? d - (P_ - 1) : 0;
            int j_hi = (d < H_ - 1) ? d : H_ - 1;
            int ncells = j_hi - j_lo + 1;
            k_gates<<<ncells * 32, 256, 0, stream>>>(d, ncells, wsb);
            k_cond<<<ncells * 8, 256, 0, stream>>>(d, bch, bcc, wsb);
        }
        float* T1 = (float*)(wsb + OFF_T1);
        float* T2 = (float*)(wsb + OFF_T2);
        const float* hfin = (const float*)(wsb + OFF_HF) + (size_t)(H_ - 1) * 32 * D_;
        k_fc<<<64, 256, 0, stream>>>(hfin, W1, b1, T1);
        k_fc<<<64, 256, 0, stream>>>(T1, W2, b2, T2);
        k_sm<<<1, 128, 0, stream>>>(T2, W3, b3, outp);
    }
}

// Round 8
// 1842.662 us; speedup vs baseline: 2.0800x; 1.1405x over previous
//
#include <hip/hip_runtime.h>

#define P_   24
#define H_   24
#define E_   300
#define D_   512
#define TWOD 1024
#define G4   4096
#define SMEMB  27648            // p1 LDS staging

typedef __attribute__((ext_vector_type(8))) short bf16x8;
typedef __attribute__((ext_vector_type(4))) float f32x4;

__device__ __forceinline__ float bflo(unsigned w) { return __uint_as_float(w << 16); }
__device__ __forceinline__ float bfhi(unsigned w) { return __uint_as_float(w & 0xffff0000u); }
__device__ __forceinline__ unsigned short f2bf(float f) {
    unsigned int x = __float_as_uint(f);
    unsigned int r = (x + 0x7fffu + ((x >> 16) & 1u)) >> 16;
    return (unsigned short)r;
}
__device__ __forceinline__ float sigf(float x) {
    return 1.0f / (1.0f + __expf(-x));
}
__device__ __forceinline__ float tanh_f(float x) {
    return 2.0f / (1.0f + __expf(-2.0f * x)) - 1.0f;
}

// fabric-coherent relaxed agent-scope accessors. NO acquire/release in the
// hot loop (agent-acquire => buffer_inv kills warm L2). Cross-kernel plain
// data (weights, Apre/Cpre) is safe via the implicit end-of-kernel L2
// writeback; within-kernel dynamic state uses these.
#define CFENCE() asm volatile("" ::: "memory")
#define LD8(p)   __hip_atomic_load((const unsigned long long*)(p), __ATOMIC_RELAXED, __HIP_MEMORY_SCOPE_AGENT)
#define LDF(p)   __hip_atomic_load((const float*)(p), __ATOMIC_RELAXED, __HIP_MEMORY_SCOPE_AGENT)
#define LDU(p)   __hip_atomic_load((const unsigned*)(p), __ATOMIC_RELAXED, __HIP_MEMORY_SCOPE_AGENT)
#define STU(p,v) __hip_atomic_store((unsigned*)(p), (unsigned)(v), __ATOMIC_RELAXED, __HIP_MEMORY_SCOPE_AGENT)
#define STF(p,v) __hip_atomic_store((float*)(p), (float)(v), __ATOMIC_RELAXED, __HIP_MEMORY_SCOPE_AGENT)
#define AADD(p,v) __hip_atomic_fetch_add((unsigned*)(p), (unsigned)(v), __ATOMIC_RELAXED, __HIP_MEMORY_SCOPE_AGENT)

// ---------------- workspace byte offsets ----------------
// Apre/Cpre TRANSPOSED: [nt=32][row=768][gate=4][u=32] bf16 — per-XCD
// nt-slices stay L2-resident across all 47 diagonals (R7: FETCH -196MB).
#define OFF_WHHP 0u           // packed Whh bf16: [nt=32][q=4][u=32][k=1024]
#define OFF_WCHB 8388608u     // 512*1024 bf16
#define OFF_WCCB 9437184u     // 512*1024 bf16
#define OFF_APRE 10485760u    // transposed, 6.29MB
#define OFF_CPRE 16777216u    // transposed, 6.29MB
#define OFF_PX   23068672u    // 768*320 bf16
#define OFF_HX   23560192u    // 768*320 bf16
#define OFF_HBB  24051712u    // 2*24*32*512 bf16 (h state, parity buffers)
#define OFF_CBF  25624576u    // 2*24*32*512 f32  (c state)
#define OFF_H2B  28770304u    // 24*32*1024 bf16
#define OFF_C2B  30343168u    // 24*32*1024 bf16
#define OFF_HF   31916032u    // 24*32*512 f32 (final h for MLP)
#define OFF_T1   33488896u    // 32*512 f32
#define OFF_T2   33554432u    // 32*512 f32
// barrier: 32 group counter lines (g*32 u32), central (u32 1024),
// 32 group generation lines (u32 1056 + g*32). Monotonic; zeroed by k_p0.
#define OFF_BAR2 33619968u

// ============ P0: weight convert/pack + embedding gather (grid 512) ========
__global__ __launch_bounds__(256) void k_p0(
        const int* __restrict__ prem, const int* __restrict__ hyp,
        const float* __restrict__ emb, const float* __restrict__ Whh,
        const float* __restrict__ Wch, const float* __restrict__ Wcc,
        char* __restrict__ wsb) {
    unsigned short* WhhP = (unsigned short*)(wsb + OFF_WHHP);
    unsigned short* WchB = (unsigned short*)(wsb + OFF_WCHB);
    unsigned short* WccB = (unsigned short*)(wsb + OFF_WCCB);
    unsigned short* PX   = (unsigned short*)(wsb + OFF_PX);
    unsigned short* HX   = (unsigned short*)(wsb + OFF_HX);

    int gt = blockIdx.x * 256 + threadIdx.x;
    int stride = gridDim.x * 256;
    // zero barrier state via fabric stores (visible to k_loop's fabric atomics)
    if (gt < 2560) STU(&((unsigned*)(wsb + OFF_BAR2))[gt], 0u);
    // Whh: convert + permute rows n=q*1024+nt*32+u -> pr=nt*128+q*32+u
    for (int idx = gt; idx < 524288; idx += stride) {
        int n = idx >> 7;              // original row
        int k8 = (idx & 127) * 8;      // col start
        int q = n >> 10, rest = n & 1023;
        int nt = rest >> 5, u = rest & 31;
        int pr = nt * 128 + q * 32 + u;
        const float* s = Whh + (size_t)n * TWOD + k8;
        float4 va = *(const float4*)s, vb = *(const float4*)(s + 4);
        unsigned short o[8] = {f2bf(va.x), f2bf(va.y), f2bf(va.z), f2bf(va.w),
                               f2bf(vb.x), f2bf(vb.y), f2bf(vb.z), f2bf(vb.w)};
        *(uint4*)(WhhP + (size_t)pr * TWOD + k8) = *(const uint4*)o;
    }
    for (int idx = gt; idx < 131072; idx += stride) {
        int cc = idx & 65535;
        const float* s = ((idx < 65536) ? Wch : Wcc) + (size_t)cc * 8;
        unsigned short* dp = ((idx < 65536) ? WchB : WccB) + (size_t)cc * 8;
        float4 va = *(const float4*)s, vb = *(const float4*)(s + 4);
        unsigned short o[8] = {f2bf(va.x), f2bf(va.y), f2bf(va.z), f2bf(va.w),
                               f2bf(vb.x), f2bf(vb.y), f2bf(vb.z), f2bf(vb.w)};
        *(uint4*)dp = *(const uint4*)o;
    }
    for (int idx = gt; idx < 61440; idx += stride) {
        int isH = idx >= 30720 ? 1 : 0;
        int id2 = idx - isH * 30720;
        int rb = id2 / 40, c8 = (id2 % 40) * 8;
        int ri = rb >> 5, rbb = rb & 31;
        int tok = isH ? hyp[rbb * H_ + ri] : prem[rbb * P_ + ri];
        const float* s = emb + (size_t)tok * E_ + c8;
        unsigned short o[8];
        for (int e = 0; e < 8; ++e)
            o[e] = (c8 + e < E_) ? f2bf(s[e]) : (unsigned short)0;
        *(uint4*)((isH ? HX : PX) + rb * 320 + c8) = *(const uint4*)o;
    }
}

// ============ P1: Apre/Cpre GEMM, 64x128 tiles, K=320 (grid 768) ===========
// Writes TRANSPOSED layout [knt][row][g][u]; plain cached stores (flushed at
// launch boundary before k_loop reads them).
__global__ __launch_bounds__(256) void k_p1(
        const float* __restrict__ Wih, const float* __restrict__ bih,
        const float* __restrict__ bhh, char* __restrict__ wsb) {
    const unsigned short* PX = (const unsigned short*)(wsb + OFF_PX);
    const unsigned short* HX = (const unsigned short*)(wsb + OFF_HX);
    unsigned short* Apre = (unsigned short*)(wsb + OFF_APRE);
    unsigned short* Cpre = (unsigned short*)(wsb + OFF_CPRE);

    __shared__ __align__(16) unsigned char smem[SMEMB];
    const int t = threadIdx.x;
    const int lane = t & 63, wvi = t >> 6, l16 = lane & 15, quad = lane >> 4;
    const int wm = wvi >> 1, wn = wvi & 1;
    unsigned short (*At)[72] = (unsigned short (*)[72])smem;            // 64 rows
    unsigned short (*Bt)[72] = (unsigned short (*)[72])(smem + 9216);   // 128 rows

    int q = blockIdx.x;
    int x = q & 7, slot = q >> 3;
    int z = slot / 48, rem = slot % 48;
    int ntg = rem / 12, mt = rem % 12;
    int nt = ntg * 8 + x;
    const unsigned short* X = z ? HX : PX;
    int koff = z ? E_ : 0;
    unsigned short* Out = z ? Cpre : Apre;
    f32x4 acc[2][4] = {};
    int arow = t >> 2, acol = (t & 3) * 16;
    int brow = t >> 1, bcol = (t & 1) * 32;
    for (int s = 0; s < 5; ++s) {
        int k0 = s * 64;
        {
            const uint4* src = (const uint4*)(X + (size_t)(mt * 64 + arow) * 320 + k0 + acol);
            uint4* dst = (uint4*)&At[arow][acol];
            dst[0] = src[0]; dst[1] = src[1];
        }
        {
            int n = nt * 128 + brow;
            const float* wrow = Wih + (size_t)n * (2 * E_) + koff;
            unsigned short* dst = &Bt[brow][bcol];
            for (int c4 = 0; c4 < 8; ++c4) {
                int k = k0 + bcol + c4 * 4;
                if (k < E_) {
                    float4 v = *(const float4*)(wrow + k);
                    dst[c4 * 4 + 0] = f2bf(v.x); dst[c4 * 4 + 1] = f2bf(v.y);
                    dst[c4 * 4 + 2] = f2bf(v.z); dst[c4 * 4 + 3] = f2bf(v.w);
                } else {
                    dst[c4 * 4 + 0] = 0; dst[c4 * 4 + 1] = 0;
                    dst[c4 * 4 + 2] = 0; dst[c4 * 4 + 3] = 0;
                }
            }
        }
        __syncthreads();
        for (int ks = 0; ks < 2; ++ks) {
            bf16x8 a[2], bb[4];
            for (int mi = 0; mi < 2; ++mi)
                a[mi] = *(const bf16x8*)&At[wm * 32 + mi * 16 + l16][ks * 32 + quad * 8];
            for (int ni = 0; ni < 4; ++ni)
                bb[ni] = *(const bf16x8*)&Bt[wn * 64 + ni * 16 + l16][ks * 32 + quad * 8];
            for (int mi = 0; mi < 2; ++mi)
                for (int ni = 0; ni < 4; ++ni)
                    acc[mi][ni] = __builtin_amdgcn_mfma_f32_16x16x32_bf16(
                        a[mi], bb[ni], acc[mi][ni], 0, 0, 0);
        }
        __syncthreads();
    }
    for (int mi = 0; mi < 2; ++mi) {
        int rbase = mt * 64 + wm * 32 + mi * 16 + quad * 4;
        for (int ni = 0; ni < 4; ++ni) {
            int n = nt * 128 + wn * 64 + ni * 16 + l16;   // [0,4096) gate-major
            int g = n >> 10, cc = n & 1023;
            int knt = cc >> 5, u = cc & 31;
            float bias = z ? 0.0f : (bih[n] + bhh[n]);
            for (int r = 0; r < 4; ++r) {
                size_t ta = (((size_t)knt * 768 + (rbase + r)) * 4 + g) * 32 + u;
                Out[ta] = f2bf(acc[mi][ni][r] + bias);
            }
        }
    }
}

// ====== A-tile stage: 32x1024 bf16 -> LDS (64KB), XOR-swizzled rows ========
// Coherent loads in 2 batches of 8 steps (uses immediately follow issues —
// nothing to sink). byteoff = row*2048 + (colbyte ^ ((row&7)<<4)).
// dual=1: gates (left-h cols<512, lower-h cols>=512); dual=0: single src.
__device__ __forceinline__ void stageA(
        unsigned char* smem, int t,
        const unsigned short* srcL, const unsigned short* srcR) {
    const int row = t >> 3;            // 0..31
    const int cb8 = (t & 7) * 8;       // element base
    const unsigned swz = (unsigned)((row & 7) << 4);
    #pragma unroll
    for (int half = 0; half < 2; ++half) {
        unsigned long long v[16];
        #pragma unroll
        for (int s = 0; s < 8; ++s) {
            int e = cb8 + (half * 8 + s) * 64;   // 0..1023
            const unsigned short* src =
                (e < D_) ? (srcL ? srcL + e : nullptr)
                         : (srcR ? srcR + (e - D_) : nullptr);
            if (src) { v[2 * s] = LD8(src); v[2 * s + 1] = LD8(src + 4); }
            else     { v[2 * s] = 0ull;     v[2 * s + 1] = 0ull; }
        }
        #pragma unroll
        for (int s = 0; s < 8; ++s) {
            unsigned e2 = (unsigned)(cb8 + (half * 8 + s) * 64) * 2u;
            unsigned off = (unsigned)row * 2048u + (e2 ^ swz);
            *(unsigned long long*)(smem + off)     = v[2 * s];
            *(unsigned long long*)(smem + off + 8) = v[2 * s + 1];
        }
    }
}

// ====== barrier-free 32x128 K=1024 GEMM core: A from LDS, B plain-cached ===
__device__ __forceinline__ void gemm_core(
        const unsigned char* smem, int l16, int quad,
        const unsigned short* wrow0, const unsigned short* wrow1,
        f32x4 acc[2][2]) {
    const unsigned sw = (unsigned)((l16 & 7) << 4);
    const unsigned base0 = (unsigned)l16 * 2048u;
    const unsigned base1 = (unsigned)(16 + l16) * 2048u;
    #pragma unroll
    for (int kk = 0; kk < 32; ++kk) {
        unsigned cbyte = (unsigned)(kk * 64 + quad * 16);
        bf16x8 a0 = *(const bf16x8*)(smem + base0 + (cbyte ^ sw));
        bf16x8 a1 = *(const bf16x8*)(smem + base1 + (cbyte ^ sw));
        bf16x8 b0 = *(const bf16x8*)(wrow0 + kk * 32 + quad * 8);
        bf16x8 b1 = *(const bf16x8*)(wrow1 + kk * 32 + quad * 8);
        acc[0][0] = __builtin_amdgcn_mfma_f32_16x16x32_bf16(a0, b0, acc[0][0], 0, 0, 0);
        acc[0][1] = __builtin_amdgcn_mfma_f32_16x16x32_bf16(a0, b1, acc[0][1], 0, 0, 0);
        acc[1][0] = __builtin_amdgcn_mfma_f32_16x16x32_bf16(a1, b0, acc[1][0], 0, 0, 0);
        acc[1][1] = __builtin_amdgcn_mfma_f32_16x16x32_bf16(a1, b1, acc[1][1], 0, 0, 0);
    }
}

// ====== gates job: job=(cell,nt) ===========================================
__device__ __forceinline__ void gates_job(
        int d, int ncells, int j_lo, int job,
        char* __restrict__ wsb, unsigned char* smem) {
    const unsigned short* WhhP = (const unsigned short*)(wsb + OFF_WHHP);
    const unsigned short* Apre = (const unsigned short*)(wsb + OFF_APRE);
    const unsigned short* Cpre = (const unsigned short*)(wsb + OFF_CPRE);
    const unsigned short* HbB  = (const unsigned short*)(wsb + OFF_HBB);
    const float*          Cbf  = (const float*)(wsb + OFF_CBF);
    unsigned short* H2B = (unsigned short*)(wsb + OFF_H2B);
    unsigned short* C2B = (unsigned short*)(wsb + OFF_C2B);

    int x = job & 7, slot = job >> 3;
    int ntg = slot / ncells, c = slot - ntg * ncells;
    int nt = ntg * 8 + x;
    int cj = j_lo + c, ci = d - cj;

    const unsigned short* HpB = HbB + (size_t)((d + 1) & 1) * (H_ * 32 * D_);
    const float* Cp = Cbf + (size_t)((d + 1) & 1) * (H_ * 32 * D_);

    const int t = threadIdx.x;
    const int lane = t & 63, wvi = t >> 6, l16 = lane & 15, quad = lane >> 4;

    __syncthreads();   // protect previous job's smem reads
    {
        const int row = t >> 3;
        const unsigned short* srcL =
            (ci > 0) ? HpB + (size_t)(cj * 32 + row) * D_ : nullptr;
        const unsigned short* srcR =
            (cj > 0) ? HpB + (size_t)((cj - 1) * 32 + row) * D_ : nullptr;
        stageA(smem, t, srcL, srcR);
    }
    __syncthreads();

    const unsigned short* wrow0 =
        WhhP + (size_t)(nt * 128 + wvi * 32 + l16) * TWOD;
    const unsigned short* wrow1 = wrow0 + (size_t)16 * TWOD;
    f32x4 acc[2][2] = {};
    gemm_core(smem, l16, quad, wrow0, wrow1, acc);
    __syncthreads();   // A reads done before Dt overwrites smem

    // cross-wave gate exchange (gate q = wvi) then fused LSTM activation
    float* Dt = (float*)smem;   // [32][132]
    for (int mi = 0; mi < 2; ++mi)
        for (int ni = 0; ni < 2; ++ni) {
            int cc2 = wvi * 32 + ni * 16 + l16;
            int rr = mi * 16 + quad * 4;
            for (int r = 0; r < 4; ++r)
                Dt[(rr + r) * 132 + cc2] = acc[mi][ni][r];
        }
    __syncthreads();
    {
        int u2 = (t & 15) * 2, r0 = (t >> 4) * 2;
        int k = nt * 32 + u2;            // even -> 4B-aligned pairs
        for (int r = r0; r < r0 + 2; ++r) {
            // transposed [nt][row][g][u]: contiguous 256B/row, L2-local
            size_t abase = (((size_t)nt * 768 + (ci * 32 + r)) * 4) * 32 + u2;
            size_t cbase = (((size_t)nt * 768 + (cj * 32 + r)) * 4) * 32 + u2;
            unsigned ap0 = *(const unsigned*)&Apre[abase];
            unsigned ap1 = *(const unsigned*)&Apre[abase + 32];
            unsigned ap2 = *(const unsigned*)&Apre[abase + 64];
            unsigned ap3 = *(const unsigned*)&Apre[abase + 96];
            unsigned cp0 = *(const unsigned*)&Cpre[cbase];
            unsigned cp1 = *(const unsigned*)&Cpre[cbase + 32];
            unsigned cp2 = *(const unsigned*)&Cpre[cbase + 64];
            unsigned cp3 = *(const unsigned*)&Cpre[cbase + 96];
            float ccat0, ccat1;
            if (k < D_) {
                if (ci > 0) {
                    const float* cp = Cp + (size_t)(cj * 32 + r) * D_ + k;
                    ccat0 = LDF(cp); ccat1 = LDF(cp + 1);
                } else { ccat0 = 0.0f; ccat1 = 0.0f; }
            } else {
                if (cj > 0) {
                    const float* cp = Cp + (size_t)((cj - 1) * 32 + r) * D_ + (k - D_);
                    ccat0 = LDF(cp); ccat1 = LDF(cp + 1);
                } else { ccat0 = 0.0f; ccat1 = 0.0f; }
            }
            float g00 = Dt[r * 132 +      u2]     + bflo(ap0) + bflo(cp0);
            float g01 = Dt[r * 132 +      u2 + 1] + bfhi(ap0) + bfhi(cp0);
            float g10 = Dt[r * 132 + 32 + u2]     + bflo(ap1) + bflo(cp1);
            float g11 = Dt[r * 132 + 32 + u2 + 1] + bfhi(ap1) + bfhi(cp1);
            float g20 = Dt[r * 132 + 64 + u2]     + bflo(ap2) + bflo(cp2);
            float g21 = Dt[r * 132 + 64 + u2 + 1] + bfhi(ap2) + bfhi(cp2);
            float g30 = Dt[r * 132 + 96 + u2]     + bflo(ap3) + bflo(cp3);
            float g31 = Dt[r * 132 + 96 + u2 + 1] + bfhi(ap3) + bfhi(cp3);
            float c20 = sigf(g10) * ccat0 + sigf(g00) * tanh_f(g20);
            float h20 = sigf(g30) * tanh_f(c20);
            float c21 = sigf(g11) * ccat1 + sigf(g01) * tanh_f(g21);
            float h21 = sigf(g31) * tanh_f(c21);
            unsigned hw = (unsigned)f2bf(h20) | ((unsigned)f2bf(h21) << 16);
            unsigned cw = (unsigned)f2bf(c20) | ((unsigned)f2bf(c21) << 16);
            STU(&H2B[(size_t)(c * 32 + r) * TWOD + k], hw);
            STU(&C2B[(size_t)(c * 32 + r) * TWOD + k], cw);
        }
    }
    // fabric stores drained by the next barrier's syncthreads before any
    // dependent read (cond runs after gbar).
}

// ====== cond job: job=(cell, z,ntile) ======================================
__device__ __forceinline__ void cond_job(
        int d, int j_lo, int job,
        const float* __restrict__ bch, const float* __restrict__ bcc,
        char* __restrict__ wsb, unsigned char* smem) {
    const unsigned short* H2B  = (const unsigned short*)(wsb + OFF_H2B);
    const unsigned short* C2B  = (const unsigned short*)(wsb + OFF_C2B);
    const unsigned short* WchB = (const unsigned short*)(wsb + OFF_WCHB);
    const unsigned short* WccB = (const unsigned short*)(wsb + OFF_WCCB);
    unsigned short* HbB = (unsigned short*)(wsb + OFF_HBB);
    float* Cbf = (float*)(wsb + OFF_CBF);
    float* Hf  = (float*)(wsb + OFF_HF);

    int xcd = job & 7, c = job >> 3;
    int z = xcd >> 2, ntile = xcd & 3;
    const unsigned short* Ain = z ? C2B : H2B;
    const unsigned short* W = z ? WccB : WchB;
    int cj = j_lo + c;

    const int t = threadIdx.x;
    const int lane = t & 63, wvi = t >> 6, l16 = lane & 15, quad = lane >> 4;

    unsigned short* HbC = HbB + (size_t)(d & 1) * (H_ * 32 * D_);
    float* CbC = Cbf + (size_t)(d & 1) * (H_ * 32 * D_);

    __syncthreads();   // protect previous job's smem reads
    {
        const int row = t >> 3;
        const unsigned short* src = Ain + (size_t)(c * 32 + row) * TWOD;
        stageA(smem, t, src, src + D_);   // contiguous 1024 cols
    }
    __syncthreads();

    const unsigned short* wrow0 =
        W + (size_t)(ntile * 128 + wvi * 32 + l16) * TWOD;
    const unsigned short* wrow1 = wrow0 + (size_t)16 * TWOD;
    f32x4 acc[2][2] = {};
    gemm_core(smem, l16, quad, wrow0, wrow1, acc);

    for (int mi = 0; mi < 2; ++mi) {
        int rr = mi * 16 + quad * 4;
        for (int ni = 0; ni < 2; ++ni) {
            int n = ntile * 128 + wvi * 32 + ni * 16 + l16;
            float bsv = z ? bcc[n] : bch[n];
            for (int r = 0; r < 4; ++r) {
                int rb = rr + r;
                float val = acc[mi][ni][r] + bsv;
                if (z) {
                    STF(&CbC[(size_t)(cj * 32 + rb) * D_ + n], val);
                } else {
                    // pack adjacent columns (lanes l16 even/odd) into one u32
                    float pv = __shfl_xor(val, 1);
                    if ((lane & 1) == 0) {
                        unsigned w2 = (unsigned)f2bf(val) | ((unsigned)f2bf(pv) << 16);
                        STU(&HbC[(size_t)(cj * 32 + rb) * D_ + n], w2);
                    }
                    if (d == P_ + H_ - 2)
                        STF(&Hf[(size_t)(cj * 32 + rb) * D_ + n], val);
                }
            }
        }
    }
}

// ============ MLP head job bodies ==========================================
__device__ __forceinline__ void fc_job(
        const float* __restrict__ hin, const float* __restrict__ W,
        const float* __restrict__ bias, float* __restrict__ outv, int job,
        float* hsh) {
    int t = threadIdx.x;
    int row = job >> 1, cb = (job & 1) * 256;
    const float* h = hin + (size_t)row * D_;
    hsh[t * 2]     = LDF(h + t * 2);
    hsh[t * 2 + 1] = LDF(h + t * 2 + 1);
    __syncthreads();
    int col = cb + t;
    const float* w = W + (size_t)col * D_;
    float accv = bias[col];
    for (int k = 0; k < D_; k += 4) {
        float4 wv4 = *(const float4*)(w + k);
        float4 hv = *(const float4*)(hsh + k);
        accv += hv.x * wv4.x + hv.y * wv4.y + hv.z * wv4.z + hv.w * wv4.w;
    }
    STF(&outv[(size_t)row * D_ + col], fmaxf(accv, 0.0f));
    __syncthreads();
}

__device__ __forceinline__ void sm_job(
        const float* __restrict__ T2, const float* __restrict__ W3,
        const float* __restrict__ b3, float* __restrict__ out, float* lg) {
    int t = threadIdx.x;
    if (t < 96) {
        int rb = t / 3, cls = t % 3;
        const float* h = T2 + (size_t)rb * D_;
        const float* w = W3 + (size_t)cls * D_;
        float accv = b3[cls];
        for (int k = 0; k < D_; k += 4) {
            float4 wv4 = *(const float4*)(w + k);
            accv += LDF(h + k) * wv4.x + LDF(h + k + 1) * wv4.y +
                    LDF(h + k + 2) * wv4.z + LDF(h + k + 3) * wv4.w;
        }
        lg[rb * 3 + cls] = accv;
    }
    __syncthreads();
    if (t < 32) {
        float a = lg[t * 3 + 0], bq = lg[t * 3 + 1], cq = lg[t * 3 + 2];
        float m = fmaxf(a, fmaxf(bq, cq));
        float ea = __expf(a - m), eb = __expf(bq - m), ec = __expf(cq - m);
        float s = 1.0f / (ea + eb + ec);
        out[t * 3 + 0] = ea * s;
        out[t * 3 + 1] = eb * s;
        out[t * 3 + 2] = ec * s;
    }
}

// ============ lightweight monotonic 2-level grid barrier ===================
// No acquire/release (no L2 inv/wb). 32 arrival groups; monotonic counters;
// zeroed by k_p0 each run. Liveness: all blocks co-resident by construction
// (grid = 2 blocks/CU x 256 CUs, launch_bounds-guaranteed occupancy).
__device__ __forceinline__ void gbar(unsigned* bs, unsigned idx, int grid) {
    __syncthreads();      // drains each wave's outstanding (fabric) stores
    if (threadIdx.x == 0) {
        unsigned g = blockIdx.x & 31u;
        unsigned gs = (unsigned)grid >> 5;
        CFENCE();
        unsigned old = AADD(bs + g * 32, 1u);
        CFENCE();
        if (old == (idx + 1u) * gs - 1u) {
            unsigned oc = AADD(bs + 1024, 1u);
            CFENCE();
            if (oc == (idx + 1u) * 32u - 1u) {
                #pragma unroll
                for (unsigned gg = 0; gg < 32; ++gg)
                    STU(bs + 1056 + gg * 32, idx + 1u);
            }
        }
        CFENCE();
        while (LDU(bs + 1056 + g * 32) <= idx)
            __builtin_amdgcn_s_sleep(2);
        CFENCE();
    }
    __syncthreads();
}

// ============ persistent kernel (PLAIN launch — graph-capturable) ==========
// 64KB LDS => exactly 2 blocks/CU; grid 512 = 2x256 CUs co-resident.
__global__ __launch_bounds__(256, 2) void k_loop(
        const float* __restrict__ bch, const float* __restrict__ bcc,
        const float* __restrict__ W1, const float* __restrict__ b1,
        const float* __restrict__ W2, const float* __restrict__ b2,
        const float* __restrict__ W3, const float* __restrict__ b3,
        float* __restrict__ outp, char* __restrict__ wsb) {
    __shared__ __align__(16) unsigned char smem[65536];
    unsigned* bs = (unsigned*)(wsb + OFF_BAR2);
    const int grid = gridDim.x;
    unsigned bidx = 0;
    for (int d = 0; d < P_ + H_ - 1; ++d) {
        int j_lo = (d > P_ - 1) ? d - (P_ - 1) : 0;
        int j_hi = (d < H_ - 1) ? d : H_ - 1;
        int ncells = j_hi - j_lo + 1;
        for (int job = blockIdx.x; job < ncells * 32; job += grid)
            gates_job(d, ncells, j_lo, job, wsb, smem);
        gbar(bs, bidx++, grid);
        for (int job = blockIdx.x; job < ncells * 8; job += grid)
            cond_job(d, j_lo, job, bch, bcc, wsb, smem);
        gbar(bs, bidx++, grid);
    }
    // MLP head folded in
    const float* hfin = (const float*)(wsb + OFF_HF) + (size_t)(H_ - 1) * 32 * D_;
    float* T1 = (float*)(wsb + OFF_T1);
    float* T2 = (float*)(wsb + OFF_T2);
    __syncthreads();
    if (blockIdx.x < 64) fc_job(hfin, W1, b1, T1, blockIdx.x, (float*)smem);
    gbar(bs, bidx++, grid);
    if (blockIdx.x < 64) fc_job(T1, W2, b2, T2, blockIdx.x, (float*)smem);
    gbar(bs, bidx++, grid);
    if (blockIdx.x == 0) sm_job(T2, W3, b3, outp, (float*)smem);
}

// ---------------------------------------------------------------------------
extern "C" void kernel_launch(void* const* d_in, const int* in_sizes, int n_in,
                              void* d_out, int out_size, void* d_ws, size_t ws_size,
                              hipStream_t stream) {
    (void)in_sizes; (void)n_in; (void)out_size; (void)ws_size;

    const int* prem = (const int*)d_in[0];
    const int* hyp  = (const int*)d_in[1];
    const float* emb = (const float*)d_in[2];
    const float* Wih = (const float*)d_in[3];
    const float* Whh = (const float*)d_in[4];
    const float* bih = (const float*)d_in[5];
    const float* bhh = (const float*)d_in[6];
    const float* Wch = (const float*)d_in[7];
    const float* bch = (const float*)d_in[8];
    const float* Wcc = (const float*)d_in[9];
    const float* bcc = (const float*)d_in[10];
    const float* W1  = (const float*)d_in[11];
    const float* b1  = (const float*)d_in[12];
    const float* W2  = (const float*)d_in[13];
    const float* b2  = (const float*)d_in[14];
    const float* W3  = (const float*)d_in[15];
    const float* b3  = (const float*)d_in[16];
    float* outp = (float*)d_out;
    char* wsb = (char*)d_ws;

    k_p0<<<512, 256, 0, stream>>>(prem, hyp, emb, Whh, Wch, Wcc, wsb);
    k_p1<<<768, 256, 0, stream>>>(Wih, bih, bhh, wsb);
    // plain launch: co-residency guaranteed (2 blocks/CU x 256 CUs = 512)
    k_loop<<<512, 256, 0, stream>>>(bch, bcc, W1, b1, W2, b2, W3, b3,
                                    outp, wsb);
}

// Round 9
// 1780.187 us; speedup vs baseline: 2.1530x; 1.0351x over previous
//
#include <hip/hip_runtime.h>

#define P_   24
#define H_   24
#define E_   300
#define D_   512
#define TWOD 1024
#define G4   4096
#define SMEMB  27648            // p1 LDS staging

typedef __attribute__((ext_vector_type(8))) short bf16x8;
typedef __attribute__((ext_vector_type(4))) float f32x4;

__device__ __forceinline__ float bflo(unsigned w) { return __uint_as_float(w << 16); }
__device__ __forceinline__ float bfhi(unsigned w) { return __uint_as_float(w & 0xffff0000u); }
__device__ __forceinline__ unsigned short f2bf(float f) {
    unsigned int x = __float_as_uint(f);
    unsigned int r = (x + 0x7fffu + ((x >> 16) & 1u)) >> 16;
    return (unsigned short)r;
}
__device__ __forceinline__ float sigf(float x) {
    return 1.0f / (1.0f + __expf(-x));
}
__device__ __forceinline__ float tanh_f(float x) {
    return 2.0f / (1.0f + __expf(-2.0f * x)) - 1.0f;
}

// fabric-coherent relaxed agent-scope accessors. NO acquire/release in the
// hot loop (agent-acquire => buffer_inv kills warm L2). Cross-kernel plain
// data (weights, Apre/Cpre) is safe via the launch-boundary L2 writeback;
// within-kernel dynamic state uses these.
#define CFENCE() asm volatile("" ::: "memory")
#define LD8(p)   __hip_atomic_load((const unsigned long long*)(p), __ATOMIC_RELAXED, __HIP_MEMORY_SCOPE_AGENT)
#define LDF(p)   __hip_atomic_load((const float*)(p), __ATOMIC_RELAXED, __HIP_MEMORY_SCOPE_AGENT)
#define LDU(p)   __hip_atomic_load((const unsigned*)(p), __ATOMIC_RELAXED, __HIP_MEMORY_SCOPE_AGENT)
#define STU(p,v) __hip_atomic_store((unsigned*)(p), (unsigned)(v), __ATOMIC_RELAXED, __HIP_MEMORY_SCOPE_AGENT)
#define STF(p,v) __hip_atomic_store((float*)(p), (float)(v), __ATOMIC_RELAXED, __HIP_MEMORY_SCOPE_AGENT)
#define AADD(p,v) __hip_atomic_fetch_add((unsigned*)(p), (unsigned)(v), __ATOMIC_RELAXED, __HIP_MEMORY_SCOPE_AGENT)

// ---------------- workspace byte offsets ----------------
// Apre/Cpre TRANSPOSED: [nt=32][row=768][gate=4][u=32] bf16 — per-XCD
// nt-slices stay L2-resident across all 47 diagonals (R7: FETCH -196MB).
#define OFF_WHHP 0u           // packed Whh bf16: [nt=32][q=4][u=32][k=1024]
#define OFF_WCHB 8388608u     // 512*1024 bf16
#define OFF_WCCB 9437184u     // 512*1024 bf16
#define OFF_APRE 10485760u    // transposed, 6.29MB
#define OFF_CPRE 16777216u    // transposed, 6.29MB
#define OFF_PX   23068672u    // 768*320 bf16
#define OFF_HX   23560192u    // 768*320 bf16
#define OFF_HBB  24051712u    // 2*24*32*512 bf16 (h state, parity buffers)
#define OFF_CBF  25624576u    // 2*24*32*512 f32  (c state)
#define OFF_H2B  28770304u    // 24*32*1024 bf16
#define OFF_C2B  30343168u    // 24*32*1024 bf16
#define OFF_HF   31916032u    // 24*32*512 f32 (final h for MLP)
#define OFF_T1   33488896u    // 32*512 f32
#define OFF_T2   33554432u    // 32*512 f32
// barrier: 32 group counter lines (g*32 u32), central (u32 1024),
// 32 group generation lines (u32 1056 + g*32). Monotonic; zeroed by k_p0.
#define OFF_BAR2 33619968u

// ============ P0: weight convert/pack + embedding gather (grid 512) ========
__global__ __launch_bounds__(256) void k_p0(
        const int* __restrict__ prem, const int* __restrict__ hyp,
        const float* __restrict__ emb, const float* __restrict__ Whh,
        const float* __restrict__ Wch, const float* __restrict__ Wcc,
        char* __restrict__ wsb) {
    unsigned short* WhhP = (unsigned short*)(wsb + OFF_WHHP);
    unsigned short* WchB = (unsigned short*)(wsb + OFF_WCHB);
    unsigned short* WccB = (unsigned short*)(wsb + OFF_WCCB);
    unsigned short* PX   = (unsigned short*)(wsb + OFF_PX);
    unsigned short* HX   = (unsigned short*)(wsb + OFF_HX);

    int gt = blockIdx.x * 256 + threadIdx.x;
    int stride = gridDim.x * 256;
    // zero barrier state via fabric stores (visible to k_loop's fabric atomics)
    if (gt < 2560) STU(&((unsigned*)(wsb + OFF_BAR2))[gt], 0u);
    // Whh: convert + permute rows n=q*1024+nt*32+u -> pr=nt*128+q*32+u
    for (int idx = gt; idx < 524288; idx += stride) {
        int n = idx >> 7;              // original row
        int k8 = (idx & 127) * 8;      // col start
        int q = n >> 10, rest = n & 1023;
        int nt = rest >> 5, u = rest & 31;
        int pr = nt * 128 + q * 32 + u;
        const float* s = Whh + (size_t)n * TWOD + k8;
        float4 va = *(const float4*)s, vb = *(const float4*)(s + 4);
        unsigned short o[8] = {f2bf(va.x), f2bf(va.y), f2bf(va.z), f2bf(va.w),
                               f2bf(vb.x), f2bf(vb.y), f2bf(vb.z), f2bf(vb.w)};
        *(uint4*)(WhhP + (size_t)pr * TWOD + k8) = *(const uint4*)o;
    }
    for (int idx = gt; idx < 131072; idx += stride) {
        int cc = idx & 65535;
        const float* s = ((idx < 65536) ? Wch : Wcc) + (size_t)cc * 8;
        unsigned short* dp = ((idx < 65536) ? WchB : WccB) + (size_t)cc * 8;
        float4 va = *(const float4*)s, vb = *(const float4*)(s + 4);
        unsigned short o[8] = {f2bf(va.x), f2bf(va.y), f2bf(va.z), f2bf(va.w),
                               f2bf(vb.x), f2bf(vb.y), f2bf(vb.z), f2bf(vb.w)};
        *(uint4*)dp = *(const uint4*)o;
    }
    for (int idx = gt; idx < 61440; idx += stride) {
        int isH = idx >= 30720 ? 1 : 0;
        int id2 = idx - isH * 30720;
        int rb = id2 / 40, c8 = (id2 % 40) * 8;
        int ri = rb >> 5, rbb = rb & 31;
        int tok = isH ? hyp[rbb * H_ + ri] : prem[rbb * P_ + ri];
        const float* s = emb + (size_t)tok * E_ + c8;
        unsigned short o[8];
        for (int e = 0; e < 8; ++e)
            o[e] = (c8 + e < E_) ? f2bf(s[e]) : (unsigned short)0;
        *(uint4*)((isH ? HX : PX) + rb * 320 + c8) = *(const uint4*)o;
    }
}

// ============ P1: Apre/Cpre GEMM, 64x128 tiles, K=320 (grid 768) ===========
// Writes TRANSPOSED layout [knt][row][g][u]; plain cached stores (flushed at
// launch boundary before k_loop reads them).
__global__ __launch_bounds__(256) void k_p1(
        const float* __restrict__ Wih, const float* __restrict__ bih,
        const float* __restrict__ bhh, char* __restrict__ wsb) {
    const unsigned short* PX = (const unsigned short*)(wsb + OFF_PX);
    const unsigned short* HX = (const unsigned short*)(wsb + OFF_HX);
    unsigned short* Apre = (unsigned short*)(wsb + OFF_APRE);
    unsigned short* Cpre = (unsigned short*)(wsb + OFF_CPRE);

    __shared__ __align__(16) unsigned char smem[SMEMB];
    const int t = threadIdx.x;
    const int lane = t & 63, wvi = t >> 6, l16 = lane & 15, quad = lane >> 4;
    const int wm = wvi >> 1, wn = wvi & 1;
    unsigned short (*At)[72] = (unsigned short (*)[72])smem;            // 64 rows
    unsigned short (*Bt)[72] = (unsigned short (*)[72])(smem + 9216);   // 128 rows

    int q = blockIdx.x;
    int x = q & 7, slot = q >> 3;
    int z = slot / 48, rem = slot % 48;
    int ntg = rem / 12, mt = rem % 12;
    int nt = ntg * 8 + x;
    const unsigned short* X = z ? HX : PX;
    int koff = z ? E_ : 0;
    unsigned short* Out = z ? Cpre : Apre;
    f32x4 acc[2][4] = {};
    int arow = t >> 2, acol = (t & 3) * 16;
    int brow = t >> 1, bcol = (t & 1) * 32;
    for (int s = 0; s < 5; ++s) {
        int k0 = s * 64;
        {
            const uint4* src = (const uint4*)(X + (size_t)(mt * 64 + arow) * 320 + k0 + acol);
            uint4* dst = (uint4*)&At[arow][acol];
            dst[0] = src[0]; dst[1] = src[1];
        }
        {
            int n = nt * 128 + brow;
            const float* wrow = Wih + (size_t)n * (2 * E_) + koff;
            unsigned short* dst = &Bt[brow][bcol];
            for (int c4 = 0; c4 < 8; ++c4) {
                int k = k0 + bcol + c4 * 4;
                if (k < E_) {
                    float4 v = *(const float4*)(wrow + k);
                    dst[c4 * 4 + 0] = f2bf(v.x); dst[c4 * 4 + 1] = f2bf(v.y);
                    dst[c4 * 4 + 2] = f2bf(v.z); dst[c4 * 4 + 3] = f2bf(v.w);
                } else {
                    dst[c4 * 4 + 0] = 0; dst[c4 * 4 + 1] = 0;
                    dst[c4 * 4 + 2] = 0; dst[c4 * 4 + 3] = 0;
                }
            }
        }
        __syncthreads();
        for (int ks = 0; ks < 2; ++ks) {
            bf16x8 a[2], bb[4];
            for (int mi = 0; mi < 2; ++mi)
                a[mi] = *(const bf16x8*)&At[wm * 32 + mi * 16 + l16][ks * 32 + quad * 8];
            for (int ni = 0; ni < 4; ++ni)
                bb[ni] = *(const bf16x8*)&Bt[wn * 64 + ni * 16 + l16][ks * 32 + quad * 8];
            for (int mi = 0; mi < 2; ++mi)
                for (int ni = 0; ni < 4; ++ni)
                    acc[mi][ni] = __builtin_amdgcn_mfma_f32_16x16x32_bf16(
                        a[mi], bb[ni], acc[mi][ni], 0, 0, 0);
        }
        __syncthreads();
    }
    for (int mi = 0; mi < 2; ++mi) {
        int rbase = mt * 64 + wm * 32 + mi * 16 + quad * 4;
        for (int ni = 0; ni < 4; ++ni) {
            int n = nt * 128 + wn * 64 + ni * 16 + l16;   // [0,4096) gate-major
            int g = n >> 10, cc = n & 1023;
            int knt = cc >> 5, u = cc & 31;
            float bias = z ? 0.0f : (bih[n] + bhh[n]);
            for (int r = 0; r < 4; ++r) {
                size_t ta = (((size_t)knt * 768 + (rbase + r)) * 4 + g) * 32 + u;
                Out[ta] = f2bf(acc[mi][ni][r] + bias);
            }
        }
    }
}

// ====== A-half stage: 32 rows x 512 cols bf16 -> 32KB LDS, XOR-swizzled ====
// sp = this thread's first source element (row t>>3, cols (t&7)*8 + s*64),
// or nullptr -> zeros. 16 coherent loads batched, uses immediately follow.
__device__ __forceinline__ void stageA32(
        unsigned char* smem, int t, const unsigned short* sp) {
    const int row = t >> 3;            // 0..31
    const int cb = (t & 7) * 8;        // element base
    const unsigned swz = (unsigned)((row & 7) << 4);
    unsigned long long v[16];
    #pragma unroll
    for (int s = 0; s < 8; ++s) {
        if (sp) { v[2 * s] = LD8(sp + s * 64); v[2 * s + 1] = LD8(sp + s * 64 + 4); }
        else    { v[2 * s] = 0ull;             v[2 * s + 1] = 0ull; }
    }
    #pragma unroll
    for (int s = 0; s < 8; ++s) {
        unsigned e2 = (unsigned)(cb + s * 64) * 2u;
        unsigned off = (unsigned)row * 1024u + (e2 ^ swz);
        *(unsigned long long*)(smem + off)     = v[2 * s];
        *(unsigned long long*)(smem + off + 8) = v[2 * s + 1];
    }
}

// ====== barrier-free 32x128 K=512 GEMM half: A from LDS, B plain-cached ====
// w0/w1 already offset to this K-half.
__device__ __forceinline__ void gemm_half(
        const unsigned char* smem, int l16, int quad,
        const unsigned short* w0, const unsigned short* w1,
        f32x4 acc[2][2]) {
    const unsigned sw = (unsigned)((l16 & 7) << 4);
    const unsigned base0 = (unsigned)l16 * 1024u;
    const unsigned base1 = (unsigned)(16 + l16) * 1024u;
    #pragma unroll
    for (int kk = 0; kk < 16; ++kk) {
        unsigned cbyte = (unsigned)(kk * 64 + quad * 16);
        bf16x8 a0 = *(const bf16x8*)(smem + base0 + (cbyte ^ sw));
        bf16x8 a1 = *(const bf16x8*)(smem + base1 + (cbyte ^ sw));
        bf16x8 b0 = *(const bf16x8*)(w0 + kk * 32 + quad * 8);
        bf16x8 b1 = *(const bf16x8*)(w1 + kk * 32 + quad * 8);
        acc[0][0] = __builtin_amdgcn_mfma_f32_16x16x32_bf16(a0, b0, acc[0][0], 0, 0, 0);
        acc[0][1] = __builtin_amdgcn_mfma_f32_16x16x32_bf16(a0, b1, acc[0][1], 0, 0, 0);
        acc[1][0] = __builtin_amdgcn_mfma_f32_16x16x32_bf16(a1, b0, acc[1][0], 0, 0, 0);
        acc[1][1] = __builtin_amdgcn_mfma_f32_16x16x32_bf16(a1, b1, acc[1][1], 0, 0, 0);
    }
}

// ====== gates job: job=(cell,nt); K split left-h / lower-h =================
__device__ __forceinline__ void gates_job(
        int d, int ncells, int j_lo, int job,
        char* __restrict__ wsb, unsigned char* smem) {
    const unsigned short* WhhP = (const unsigned short*)(wsb + OFF_WHHP);
    const unsigned short* Apre = (const unsigned short*)(wsb + OFF_APRE);
    const unsigned short* Cpre = (const unsigned short*)(wsb + OFF_CPRE);
    const unsigned short* HbB  = (const unsigned short*)(wsb + OFF_HBB);
    const float*          Cbf  = (const float*)(wsb + OFF_CBF);
    unsigned short* H2B = (unsigned short*)(wsb + OFF_H2B);
    unsigned short* C2B = (unsigned short*)(wsb + OFF_C2B);

    int x = job & 7, slot = job >> 3;
    int ntg = slot / ncells, c = slot - ntg * ncells;
    int nt = ntg * 8 + x;
    int cj = j_lo + c, ci = d - cj;

    const unsigned short* HpB = HbB + (size_t)((d + 1) & 1) * (H_ * 32 * D_);
    const float* Cp = Cbf + (size_t)((d + 1) & 1) * (H_ * 32 * D_);

    const int t = threadIdx.x;
    const int lane = t & 63, wvi = t >> 6, l16 = lane & 15, quad = lane >> 4;
    const int row = t >> 3, cb = (t & 7) * 8;

    const unsigned short* wrow0 =
        WhhP + (size_t)(nt * 128 + wvi * 32 + l16) * TWOD;
    const unsigned short* wrow1 = wrow0 + (size_t)16 * TWOD;
    f32x4 acc[2][2] = {};

    // half 0: left-h (K = 0..511)
    __syncthreads();   // protect previous job's smem reads
    stageA32(smem, t,
             (ci > 0) ? HpB + (size_t)(cj * 32 + row) * D_ + cb : nullptr);
    __syncthreads();
    gemm_half(smem, l16, quad, wrow0, wrow1, acc);
    // half 1: lower-h (K = 512..1023)
    __syncthreads();   // all A reads of half 0 done
    stageA32(smem, t,
             (cj > 0) ? HpB + (size_t)((cj - 1) * 32 + row) * D_ + cb : nullptr);
    __syncthreads();
    gemm_half(smem, l16, quad, wrow0 + 512, wrow1 + 512, acc);
    __syncthreads();   // A reads done before Dt overwrites smem

    // cross-wave gate exchange (gate q = wvi) then fused LSTM activation
    float* Dt = (float*)smem;   // [32][132] = 16.9KB, aliases staging buffer
    for (int mi = 0; mi < 2; ++mi)
        for (int ni = 0; ni < 2; ++ni) {
            int cc2 = wvi * 32 + ni * 16 + l16;
            int rr = mi * 16 + quad * 4;
            for (int r = 0; r < 4; ++r)
                Dt[(rr + r) * 132 + cc2] = acc[mi][ni][r];
        }
    __syncthreads();
    {
        int u2 = (t & 15) * 2, r0 = (t >> 4) * 2;
        int k = nt * 32 + u2;            // even -> 4B-aligned pairs
        for (int r = r0; r < r0 + 2; ++r) {
            // transposed [nt][row][g][u]: contiguous 256B/row, L2-local
            size_t abase = (((size_t)nt * 768 + (ci * 32 + r)) * 4) * 32 + u2;
            size_t cbase = (((size_t)nt * 768 + (cj * 32 + r)) * 4) * 32 + u2;
            unsigned ap0 = *(const unsigned*)&Apre[abase];
            unsigned ap1 = *(const unsigned*)&Apre[abase + 32];
            unsigned ap2 = *(const unsigned*)&Apre[abase + 64];
            unsigned ap3 = *(const unsigned*)&Apre[abase + 96];
            unsigned cp0 = *(const unsigned*)&Cpre[cbase];
            unsigned cp1 = *(const unsigned*)&Cpre[cbase + 32];
            unsigned cp2 = *(const unsigned*)&Cpre[cbase + 64];
            unsigned cp3 = *(const unsigned*)&Cpre[cbase + 96];
            float ccat0, ccat1;
            if (k < D_) {
                if (ci > 0) {
                    const float* cp = Cp + (size_t)(cj * 32 + r) * D_ + k;
                    ccat0 = LDF(cp); ccat1 = LDF(cp + 1);
                } else { ccat0 = 0.0f; ccat1 = 0.0f; }
            } else {
                if (cj > 0) {
                    const float* cp = Cp + (size_t)((cj - 1) * 32 + r) * D_ + (k - D_);
                    ccat0 = LDF(cp); ccat1 = LDF(cp + 1);
                } else { ccat0 = 0.0f; ccat1 = 0.0f; }
            }
            float g00 = Dt[r * 132 +      u2]     + bflo(ap0) + bflo(cp0);
            float g01 = Dt[r * 132 +      u2 + 1] + bfhi(ap0) + bfhi(cp0);
            float g10 = Dt[r * 132 + 32 + u2]     + bflo(ap1) + bflo(cp1);
            float g11 = Dt[r * 132 + 32 + u2 + 1] + bfhi(ap1) + bfhi(cp1);
            float g20 = Dt[r * 132 + 64 + u2]     + bflo(ap2) + bflo(cp2);
            float g21 = Dt[r * 132 + 64 + u2 + 1] + bfhi(ap2) + bfhi(cp2);
            float g30 = Dt[r * 132 + 96 + u2]     + bflo(ap3) + bflo(cp3);
            float g31 = Dt[r * 132 + 96 + u2 + 1] + bfhi(ap3) + bfhi(cp3);
            float c20 = sigf(g10) * ccat0 + sigf(g00) * tanh_f(g20);
            float h20 = sigf(g30) * tanh_f(c20);
            float c21 = sigf(g11) * ccat1 + sigf(g01) * tanh_f(g21);
            float h21 = sigf(g31) * tanh_f(c21);
            unsigned hw = (unsigned)f2bf(h20) | ((unsigned)f2bf(h21) << 16);
            unsigned cw = (unsigned)f2bf(c20) | ((unsigned)f2bf(c21) << 16);
            STU(&H2B[(size_t)(c * 32 + r) * TWOD + k], hw);
            STU(&C2B[(size_t)(c * 32 + r) * TWOD + k], cw);
        }
    }
    // fabric stores drained before dependent reads by gbar's syncthreads.
}

// ====== cond job: job=(cell, z,ntile); K split col 0..511 / 512..1023 ======
__device__ __forceinline__ void cond_job(
        int d, int j_lo, int job,
        const float* __restrict__ bch, const float* __restrict__ bcc,
        char* __restrict__ wsb, unsigned char* smem) {
    const unsigned short* H2B  = (const unsigned short*)(wsb + OFF_H2B);
    const unsigned short* C2B  = (const unsigned short*)(wsb + OFF_C2B);
    const unsigned short* WchB = (const unsigned short*)(wsb + OFF_WCHB);
    const unsigned short* WccB = (const unsigned short*)(wsb + OFF_WCCB);
    unsigned short* HbB = (unsigned short*)(wsb + OFF_HBB);
    float* Cbf = (float*)(wsb + OFF_CBF);
    float* Hf  = (float*)(wsb + OFF_HF);

    int xcd = job & 7, c = job >> 3;
    int z = xcd >> 2, ntile = xcd & 3;
    const unsigned short* Ain = z ? C2B : H2B;
    const unsigned short* W = z ? WccB : WchB;
    int cj = j_lo + c;

    const int t = threadIdx.x;
    const int lane = t & 63, wvi = t >> 6, l16 = lane & 15, quad = lane >> 4;
    const int row = t >> 3, cb = (t & 7) * 8;

    unsigned short* HbC = HbB + (size_t)(d & 1) * (H_ * 32 * D_);
    float* CbC = Cbf + (size_t)(d & 1) * (H_ * 32 * D_);

    const unsigned short* wrow0 =
        W + (size_t)(ntile * 128 + wvi * 32 + l16) * TWOD;
    const unsigned short* wrow1 = wrow0 + (size_t)16 * TWOD;
    const unsigned short* asrc = Ain + (size_t)(c * 32 + row) * TWOD + cb;
    f32x4 acc[2][2] = {};

    __syncthreads();   // protect previous job's smem reads
    stageA32(smem, t, asrc);
    __syncthreads();
    gemm_half(smem, l16, quad, wrow0, wrow1, acc);
    __syncthreads();
    stageA32(smem, t, asrc + 512);
    __syncthreads();
    gemm_half(smem, l16, quad, wrow0 + 512, wrow1 + 512, acc);

    for (int mi = 0; mi < 2; ++mi) {
        int rr = mi * 16 + quad * 4;
        for (int ni = 0; ni < 2; ++ni) {
            int n = ntile * 128 + wvi * 32 + ni * 16 + l16;
            float bsv = z ? bcc[n] : bch[n];
            for (int r = 0; r < 4; ++r) {
                int rb = rr + r;
                float val = acc[mi][ni][r] + bsv;
                if (z) {
                    STF(&CbC[(size_t)(cj * 32 + rb) * D_ + n], val);
                } else {
                    // pack adjacent columns (lanes l16 even/odd) into one u32
                    float pv = __shfl_xor(val, 1);
                    if ((lane & 1) == 0) {
                        unsigned w2 = (unsigned)f2bf(val) | ((unsigned)f2bf(pv) << 16);
                        STU(&HbC[(size_t)(cj * 32 + rb) * D_ + n], w2);
                    }
                    if (d == P_ + H_ - 2)
                        STF(&Hf[(size_t)(cj * 32 + rb) * D_ + n], val);
                }
            }
        }
    }
}

// ============ MLP head job bodies ==========================================
__device__ __forceinline__ void fc_job(
        const float* __restrict__ hin, const float* __restrict__ W,
        const float* __restrict__ bias, float* __restrict__ outv, int job,
        float* hsh) {
    int t = threadIdx.x;
    int row = job >> 1, cb = (job & 1) * 256;
    const float* h = hin + (size_t)row * D_;
    hsh[t * 2]     = LDF(h + t * 2);
    hsh[t * 2 + 1] = LDF(h + t * 2 + 1);
    __syncthreads();
    int col = cb + t;
    const float* w = W + (size_t)col * D_;
    float accv = bias[col];
    for (int k = 0; k < D_; k += 4) {
        float4 wv4 = *(const float4*)(w + k);
        float4 hv = *(const float4*)(hsh + k);
        accv += hv.x * wv4.x + hv.y * wv4.y + hv.z * wv4.z + hv.w * wv4.w;
    }
    STF(&outv[(size_t)row * D_ + col], fmaxf(accv, 0.0f));
    __syncthreads();
}

__device__ __forceinline__ void sm_job(
        const float* __restrict__ T2, const float* __restrict__ W3,
        const float* __restrict__ b3, float* __restrict__ out, float* lg) {
    int t = threadIdx.x;
    if (t < 96) {
        int rb = t / 3, cls = t % 3;
        const float* h = T2 + (size_t)rb * D_;
        const float* w = W3 + (size_t)cls * D_;
        float accv = b3[cls];
        for (int k = 0; k < D_; k += 4) {
            float4 wv4 = *(const float4*)(w + k);
            accv += LDF(h + k) * wv4.x + LDF(h + k + 1) * wv4.y +
                    LDF(h + k + 2) * wv4.z + LDF(h + k + 3) * wv4.w;
        }
        lg[rb * 3 + cls] = accv;
    }
    __syncthreads();
    if (t < 32) {
        float a = lg[t * 3 + 0], bq = lg[t * 3 + 1], cq = lg[t * 3 + 2];
        float m = fmaxf(a, fmaxf(bq, cq));
        float ea = __expf(a - m), eb = __expf(bq - m), ec = __expf(cq - m);
        float s = 1.0f / (ea + eb + ec);
        out[t * 3 + 0] = ea * s;
        out[t * 3 + 1] = eb * s;
        out[t * 3 + 2] = ec * s;
    }
}

// ============ lightweight monotonic 2-level grid barrier ===================
// No acquire/release (no L2 inv/wb). 32 arrival groups; monotonic counters;
// zeroed by k_p0 each run. Liveness: all blocks co-resident by construction
// (grid = 3 blocks/CU x 256 CUs; 32KB LDS + ~90 VGPR allow >=4).
__device__ __forceinline__ void gbar(unsigned* bs, unsigned idx, int grid) {
    __syncthreads();      // drains each wave's outstanding (fabric) stores
    if (threadIdx.x == 0) {
        unsigned g = blockIdx.x & 31u;
        unsigned gs = (unsigned)grid >> 5;
        CFENCE();
        unsigned old = AADD(bs + g * 32, 1u);
        CFENCE();
        if (old == (idx + 1u) * gs - 1u) {
            unsigned oc = AADD(bs + 1024, 1u);
            CFENCE();
            if (oc == (idx + 1u) * 32u - 1u) {
                #pragma unroll
                for (unsigned gg = 0; gg < 32; ++gg)
                    STU(bs + 1056 + gg * 32, idx + 1u);
            }
        }
        CFENCE();
        while (LDU(bs + 1056 + g * 32) <= idx)
            __builtin_amdgcn_s_sleep(2);
        CFENCE();
    }
    __syncthreads();
}

// ============ persistent kernel (PLAIN launch — graph-capturable) ==========
// 32KB LDS => >=3 blocks/CU guaranteed; grid 768 = 3x256 co-resident.
__global__ __launch_bounds__(256, 3) void k_loop(
        const float* __restrict__ bch, const float* __restrict__ bcc,
        const float* __restrict__ W1, const float* __restrict__ b1,
        const float* __restrict__ W2, const float* __restrict__ b2,
        const float* __restrict__ W3, const float* __restrict__ b3,
        float* __restrict__ outp, char* __restrict__ wsb) {
    __shared__ __align__(16) unsigned char smem[32768];
    unsigned* bs = (unsigned*)(wsb + OFF_BAR2);
    const int grid = gridDim.x;
    unsigned bidx = 0;
    for (int d = 0; d < P_ + H_ - 1; ++d) {
        int j_lo = (d > P_ - 1) ? d - (P_ - 1) : 0;
        int j_hi = (d < H_ - 1) ? d : H_ - 1;
        int ncells = j_hi - j_lo + 1;
        for (int job = blockIdx.x; job < ncells * 32; job += grid)
            gates_job(d, ncells, j_lo, job, wsb, smem);
        gbar(bs, bidx++, grid);
        for (int job = blockIdx.x; job < ncells * 8; job += grid)
            cond_job(d, j_lo, job, bch, bcc, wsb, smem);
        gbar(bs, bidx++, grid);
    }
    // MLP head folded in
    const float* hfin = (const float*)(wsb + OFF_HF) + (size_t)(H_ - 1) * 32 * D_;
    float* T1 = (float*)(wsb + OFF_T1);
    float* T2 = (float*)(wsb + OFF_T2);
    __syncthreads();
    if (blockIdx.x < 64) fc_job(hfin, W1, b1, T1, blockIdx.x, (float*)smem);
    gbar(bs, bidx++, grid);
    if (blockIdx.x < 64) fc_job(T1, W2, b2, T2, blockIdx.x, (float*)smem);
    gbar(bs, bidx++, grid);
    if (blockIdx.x == 0) sm_job(T2, W3, b3, outp, (float*)smem);
}

// ---------------------------------------------------------------------------
extern "C" void kernel_launch(void* const* d_in, const int* in_sizes, int n_in,
                              void* d_out, int out_size, void* d_ws, size_t ws_size,
                              hipStream_t stream) {
    (void)in_sizes; (void)n_in; (void)out_size; (void)ws_size;

    const int* prem = (const int*)d_in[0];
    const int* hyp  = (const int*)d_in[1];
    const float* emb = (const float*)d_in[2];
    const float* Wih = (const float*)d_in[3];
    const float* Whh = (const float*)d_in[4];
    const float* bih = (const float*)d_in[5];
    const float* bhh = (const float*)d_in[6];
    const float* Wch = (const float*)d_in[7];
    const float* bch = (const float*)d_in[8];
    const float* Wcc = (const float*)d_in[9];
    const float* bcc = (const float*)d_in[10];
    const float* W1  = (const float*)d_in[11];
    const float* b1  = (const float*)d_in[12];
    const float* W2  = (const float*)d_in[13];
    const float* b2  = (const float*)d_in[14];
    const float* W3  = (const float*)d_in[15];
    const float* b3  = (const float*)d_in[16];
    float* outp = (float*)d_out;
    char* wsb = (char*)d_ws;

    k_p0<<<512, 256, 0, stream>>>(prem, hyp, emb, Whh, Wch, Wcc, wsb);
    k_p1<<<768, 256, 0, stream>>>(Wih, bih, bhh, wsb);
    // plain launch: co-residency guaranteed (3 blocks/CU x 256 CUs = 768)
    k_loop<<<768, 256, 0, stream>>>(bch, bcc, W1, b1, W2, b2, W3, b3,
                                    outp, wsb);
}